// Round 2
// baseline (27580.655 us; speedup 1.0000x reference)
//
#include <hip/hip_runtime.h>
#include <hip/hip_bf16.h>

#define BNC 0.99950037f   // 1/sqrt(1+1e-3), BN eval scale factor
#define GH 400
#define GW 352

// ---------------------------------------------------------------------------
// Winner grid: last voxel index wins for duplicate cells (matches np fancy-set)
// ---------------------------------------------------------------------------
__global__ void k_winner(const int* __restrict__ coors, int* __restrict__ winner, int N) {
    int i = blockIdx.x * 256 + threadIdx.x;
    if (i >= N) return;
    int d = coors[i*4+1], h = coors[i*4+2], w = coors[i*4+3];
    atomicMax(&winner[(d*GH + h)*GW + w], i);
}

// ---------------------------------------------------------------------------
// Per-strip voxel lists: voxel with input row h touches conv1 output rows
// {h-1,h,h+1}; strip s needs output rows [s*SH-2, s*SH+SH+2)  =>  h in
// [s*SH-3, s*SH+SH+3). A voxel lands in at most 2 strips.
// ---------------------------------------------------------------------------
__global__ void k_lists(const int* __restrict__ coors, int* __restrict__ list,
                        int* __restrict__ cnt, int N, int SH, int NS) {
    int i = blockIdx.x * 256 + threadIdx.x;
    if (i >= N) return;
    int h = coors[i*4+2];
    for (int s = 0; s < NS; ++s) {
        int lo = s*SH - 3, hi = s*SH + SH + 3;
        if (h >= lo && h < hi) {
            int p = atomicAdd(&cnt[s], 1);
            list[(long)s*N + p] = i;
        }
    }
}

// ---------------------------------------------------------------------------
// Weight transpose: OIDHW -> [tap][ci4][co][4] (float4-interleaved over ci)
// ---------------------------------------------------------------------------
__global__ void k_tr_w(const float* __restrict__ w, float* __restrict__ wt, int CI, int CO) {
    int idx = blockIdx.x * 256 + threadIdx.x;
    int total = 27 * CI * CO;
    if (idx >= total) return;
    int j   = idx & 3;
    int t1  = idx >> 2;
    int co  = t1 % CO;
    int t2  = t1 / CO;
    int ci4 = t2 % (CI/4);
    int tap = t2 / (CI/4);
    int ci  = ci4*4 + j;
    wt[idx] = w[(co*CI + ci)*27 + tap];
}

// ---------------------------------------------------------------------------
// VFE: one block (128 thr) per voxel. Faithful-to-reference quirks:
// mean over ALL 35 rows / num_voxels; per-layer max over ALL rows pre-mask.
// ---------------------------------------------------------------------------
__global__ __launch_bounds__(128) void k_vfe(
    const float* __restrict__ feats, const int* __restrict__ nvox,
    const float* __restrict__ w1, const float* __restrict__ g1g, const float* __restrict__ b1g,
    const float* __restrict__ w2, const float* __restrict__ g2g, const float* __restrict__ b2g,
    const float* __restrict__ wlg, const float* __restrict__ glg, const float* __restrict__ blg,
    float* __restrict__ voxelwise)
{
    __shared__ float P[13320];
    float* X2    = P;          // [35][128]
    float* WL    = P + 4480;   // [128][33]
    float* AGG   = P + 8704;   // [128]
    float* MEANS = P + 8832;   // [3]
    float* B     = P + 8840;   // overlay region (4480 floats)
    float* F  = B;             // [35][8]  (cols 0..3 feat, 4..6 rel)
    float* W1 = B + 280;       // [16][8]
    float* G1 = B + 408, *B1 = B + 424;
    float* X1 = B + 440;       // [35][32]
    float* W2 = B + 1560;      // [64][33]
    float* G2 = B + 3672, *B2 = B + 3736;
    float* YL = B;             // [35][128] overlays F/W1/X1/W2 in linear phase

    int tid = threadIdx.x;
    int vox = blockIdx.x;
    int nv  = nvox[vox];

    const float* fsrc = feats + (long)vox * 140;
    for (int idx = tid; idx < 140; idx += 128) { int t = idx>>2, c = idx&3; F[t*8+c] = fsrc[idx]; }
    if (tid < 112) { int u = tid/7, c = tid - u*7; W1[u*8+c] = w1[tid]; }
    if (tid < 16)  { G1[tid] = g1g[tid]; B1[tid] = b1g[tid]; }
    __syncthreads();

    if (tid < 3) {
        float s = 0.f;
        for (int t = 0; t < 35; ++t) s += F[t*8 + tid];
        MEANS[tid] = s / (float)nv;
    }
    __syncthreads();
    for (int idx = tid; idx < 105; idx += 128) { int t = idx/3, c = idx - t*3; F[t*8+4+c] = F[t*8+c] - MEANS[c]; }
    __syncthreads();

    // ---- VFE layer 1: [35,7] @ [16,7]^T, bn+relu ----
    for (int idx = tid; idx < 560; idx += 128) {
        int t = idx >> 4, u = idx & 15;
        float a = 0.f;
        #pragma unroll
        for (int c = 0; c < 7; ++c) a += F[t*8+c] * W1[u*8+c];
        X1[t*32+u] = fmaxf(a * (G1[u]*BNC) + B1[u], 0.f);
    }
    __syncthreads();
    if (tid < 16) {
        float m = 0.f;
        for (int t = 0; t < 35; ++t) m = fmaxf(m, X1[t*32+tid]);
        AGG[tid] = m;
    }
    __syncthreads();
    for (int idx = tid; idx < 1120; idx += 128) {
        int t = idx >> 5, j = idx & 31;
        bool v = t < nv;
        if (j < 16) { if (!v) X1[idx] = 0.f; }
        else        X1[idx] = v ? AGG[j-16] : 0.f;
    }
    for (int idx = tid; idx < 2048; idx += 128) { int u = idx>>5, c = idx&31; W2[u*33+c] = w2[idx]; }
    if (tid < 64) { G2[tid] = g2g[tid]; B2[tid] = b2g[tid]; }
    __syncthreads();

    // ---- VFE layer 2: [35,32] @ [64,32]^T ----
    if (tid < 64) {
        int u = tid;
        float su = G2[u]*BNC, bu = B2[u];
        for (int t = 0; t < 35; ++t) {
            float a = 0.f;
            #pragma unroll
            for (int c = 0; c < 32; ++c) a += X1[t*32+c] * W2[u*33+c];
            X2[t*128+u] = fmaxf(a*su + bu, 0.f);
        }
    }
    __syncthreads();
    if (tid < 64) {
        float m = 0.f;
        for (int t = 0; t < 35; ++t) m = fmaxf(m, X2[t*128+tid]);
        AGG[tid] = m;
    }
    __syncthreads();
    for (int idx = tid; idx < 4480; idx += 128) {
        int t = idx >> 7, j = idx & 127;
        bool v = t < nv;
        if (j < 64) { if (!v) X2[idx] = 0.f; }
        else        X2[idx] = v ? AGG[j-64] : 0.f;
    }
    __syncthreads();  // X1/W2 region now dead -> becomes YL

    // ---- Linear: [35,128] @ [128,128]^T, chunked over c ----
    for (int c0 = 0; c0 < 128; c0 += 32) {
        for (int idx = tid; idx < 4096; idx += 128) {
            int u = idx >> 5, j = idx & 31;
            WL[u*33+j] = wlg[u*128 + c0 + j];
        }
        __syncthreads();
        {
            int u = tid;
            float wreg[32];
            #pragma unroll
            for (int j = 0; j < 32; ++j) wreg[j] = WL[u*33+j];
            for (int t = 0; t < 35; ++t) {
                const float4* xv = (const float4*)(X2 + t*128 + c0);
                float a = 0.f;
                #pragma unroll
                for (int q = 0; q < 8; ++q) {
                    float4 x4 = xv[q];
                    a += x4.x*wreg[q*4] + x4.y*wreg[q*4+1] + x4.z*wreg[q*4+2] + x4.w*wreg[q*4+3];
                }
                if (c0 == 0) YL[t*128+u] = a; else YL[t*128+u] += a;
            }
        }
        __syncthreads();
    }

    {
        int u = tid;
        float su = glg[u]*BNC, bu = blg[u];
        float m = 0.f;
        for (int t = 0; t < nv; ++t) m = fmaxf(m, fmaxf(YL[t*128+u]*su + bu, 0.f));
        voxelwise[(long)vox*128 + u] = m;
    }
}

// ---------------------------------------------------------------------------
// conv1 as sparse scatter into one H-strip's accumulator.
// accS layout: [5][AR][352][64], row r <-> global conv1-out row h_lo + r.
// 32 voxels/block from this strip's compacted list; blocks past cnt exit
// before staging any weights.
// ---------------------------------------------------------------------------
__global__ __launch_bounds__(256) void k_scat(
    const float4* __restrict__ voxf4, const int* __restrict__ coors,
    const int* __restrict__ winner, const float4* __restrict__ Wt1,
    float* __restrict__ accS, const int* __restrict__ list,
    const int* __restrict__ cnt, int h_lo, int AR)
{
    __shared__ float4 sW[2048];     // [ci4=32][co=64]  32KB
    __shared__ float4 sF[32][32];   // 32 voxels x 128ch 16KB
    __shared__ int sI[32], sD[32], sH_[32], sWc[32], sV[32];
    int tid = threadIdx.x;
    int cn = cnt[0];
    int v0 = blockIdx.x * 32;
    if (v0 >= cn) return;

    if (tid < 32) {
        int slot = v0 + tid;
        int i = -1, d = 0, h = 0, w = 0, ok = 0;
        if (slot < cn) {
            i = list[slot];
            d = coors[i*4+1]; h = coors[i*4+2]; w = coors[i*4+3];
            ok = (winner[(d*GH + h)*GW + w] == i);
        }
        sI[tid] = i; sD[tid] = d; sH_[tid] = h; sWc[tid] = w; sV[tid] = ok;
    }
    __syncthreads();
    for (int idx = tid; idx < 1024; idx += 256) {
        int v = idx >> 5, c = idx & 31;
        int vi = sI[v];
        if (vi >= 0) sF[v][c] = voxf4[(long)vi*32 + c];
    }

    int co = tid & 63, wv = tid >> 6;
    for (int tap = 0; tap < 27; ++tap) {
        __syncthreads();   // covers sF (tap 0) and prev-tap sW readers
        for (int idx = tid; idx < 2048; idx += 256) sW[idx] = Wt1[tap*2048 + idx];
        __syncthreads();
        int kd = tap/9, kh = (tap/3)%3, kw = tap%3;
        for (int s8 = 0; s8 < 8; ++s8) {
            int v = wv*8 + s8;                 // wave-uniform
            int od2 = sD[v] + 1 - kd;          // = 2*do if valid
            int oh  = sH_[v] + 1 - kh;
            int ow  = sWc[v] + 1 - kw;
            bool ok = sV[v] && !(od2 & 1) && (unsigned)od2 < 10u
                      && oh >= 0 && oh < GH && oh >= h_lo && oh < h_lo + AR
                      && (unsigned)ow < (unsigned)GW;
            if (ok) {
                float a = 0.f;
                #pragma unroll
                for (int c4 = 0; c4 < 32; ++c4) {
                    float4 wq = sW[c4*64 + co];
                    float4 f4 = sF[v][c4];
                    a += f4.x*wq.x + f4.y*wq.y + f4.z*wq.z + f4.w*wq.w;
                }
                long cell = (long)((od2>>1)*AR + (oh - h_lo))*GW + ow;
                atomicAdd(&accS[cell*64 + co], a);
            }
        }
    }
}

// ---------------------------------------------------------------------------
// Dense direct conv3d over one H-strip. Cin=Cout=64, channels-last input
// [D][rows][352][64] with row 0 <-> global row src_h0. 3x3 HW taps, pad=1 in
// H/W via global-coordinate guards. Optional fused input activation (bn+relu
// of PREVIOUS layer) on staged reads; fused bn+relu on output writes.
// ---------------------------------------------------------------------------
__global__ __launch_bounds__(256) void k_conv(
    const float* __restrict__ src, int src_h0, long src_dpitch,
    float* __restrict__ dst, int dst_h0, long sC, long sD, long sH, long sW,
    const float4* __restrict__ Wt,
    const float* __restrict__ gin, const float* __restrict__ bin,   // nullable
    const float* __restrict__ gout, const float* __restrict__ bout,
    int D_in, int d_stride, int d_pad, int y0)
{
    int oh = y0 + (int)blockIdx.y;
    if (oh < 0 || oh >= GH) return;            // uniform early-out (strip edges)

    __shared__ float4 sWl[3072];     // 3 kw slices of [ci4=16][co=64]  48KB
    __shared__ float4 sIn[34*16];    // [iw=34][ci4=16]                 8.5KB
    __shared__ float  sGin[64], sBin[64];
    int tid = threadIdx.x;
    int w0 = blockIdx.x * 32, doo = blockIdx.z;
    int co = tid & 63, wg = tid >> 6;
    bool hasact = (gin != nullptr);
    if (tid < 64) { sGin[tid] = hasact ? gin[tid]*BNC : 1.f; sBin[tid] = hasact ? bin[tid] : 0.f; }

    float acc[8];
    #pragma unroll
    for (int j = 0; j < 8; ++j) acc[j] = 0.f;

    for (int kd = 0; kd < 3; ++kd) {
        int dp = doo*d_stride + kd - d_pad;
        if (dp < 0 || dp >= D_in) continue;     // d zero-padding (uniform)
        for (int kh = 0; kh < 3; ++kh) {
            int hp = oh + kh - 1;
            __syncthreads();   // protect previous tap's LDS reads
            {
                float* sInF = (float*)sIn;
                const float* srow = src + dp*src_dpitch + (long)(hp - src_h0) * (GW*64);
                bool vh = (hp >= 0 && hp < GH);
                for (int idx = tid; idx < 34*64; idx += 256) {
                    int iw = idx >> 6, ci = idx & 63;
                    int wi = w0 - 1 + iw;
                    float val = 0.f;
                    if (vh && (unsigned)wi < (unsigned)GW) {
                        val = srow[(long)wi*64 + ci];
                        val = fmaxf(val * sGin[ci] + sBin[ci], 0.f);   // identity if gin==null
                    }
                    sInF[idx] = val;
                }
                const float4* wsrc = Wt + (long)(kd*3 + kh)*3*1024;
                for (int idx = tid; idx < 3072; idx += 256) sWl[idx] = wsrc[idx];
            }
            __syncthreads();
            #pragma unroll
            for (int kw = 0; kw < 3; ++kw) {
                const float4* WR = sWl + kw*1024;
                #pragma unroll
                for (int c4 = 0; c4 < 16; ++c4) {
                    float4 wq = WR[c4*64 + co];
                    #pragma unroll
                    for (int j = 0; j < 8; ++j) {
                        float4 a = sIn[(wg*8 + j + kw)*16 + c4];
                        acc[j] += a.x*wq.x + a.y*wq.y + a.z*wq.z + a.w*wq.w;
                    }
                }
            }
        }
    }

    float so = gout[co]*BNC, bo = bout[co];
    long base = (long)co*sC + (long)doo*sD + (long)(oh - dst_h0)*sH;
    #pragma unroll
    for (int j = 0; j < 8; ++j) {
        int w = w0 + wg*8 + j;
        dst[base + (long)w*sW] = fmaxf(acc[j]*so + bo, 0.f);
    }
}

// ---------------------------------------------------------------------------
extern "C" void kernel_launch(void* const* d_in, const int* in_sizes, int n_in,
                              void* d_out, int out_size, void* d_ws, size_t ws_size,
                              hipStream_t stream)
{
    const float* feats = (const float*)d_in[0];
    const int*   nvox  = (const int*)d_in[1];
    const int*   coors = (const int*)d_in[2];
    const float* w1  = (const float*)d_in[4];
    const float* g1  = (const float*)d_in[5];
    const float* b1  = (const float*)d_in[6];
    const float* w2  = (const float*)d_in[7];
    const float* g2  = (const float*)d_in[8];
    const float* b2  = (const float*)d_in[9];
    const float* wl  = (const float*)d_in[10];
    const float* gl  = (const float*)d_in[11];
    const float* bl  = (const float*)d_in[12];
    const float* wc1 = (const float*)d_in[13];
    const float* gc1 = (const float*)d_in[14];
    const float* bc1 = (const float*)d_in[15];
    const float* wc2 = (const float*)d_in[16];
    const float* gc2 = (const float*)d_in[17];
    const float* bc2 = (const float*)d_in[18];
    const float* wc3 = (const float*)d_in[19];
    const float* gc3 = (const float*)d_in[20];
    const float* bc3 = (const float*)d_in[21];

    int N = in_sizes[1];            // 20000 voxels

    auto al = [](size_t b) { return (b + 255) & ~(size_t)255; };

    // --- choose strip count NS: smallest NS whose workspace fits ws_size ---
    size_t winB = al((size_t)10*GH*GW*4);
    size_t voxB = al((size_t)N*128*4);
    size_t w1B  = al((size_t)27*128*64*4);
    size_t w23B = al((size_t)27*64*64*4);
    int NS = 16;
    const int cand[5] = {1, 2, 4, 8, 16};
    for (int k = 0; k < 5; ++k) {
        int ns = cand[k], sh = 400/ns, ar = sh + 4, xr = sh + 2;
        size_t tot = al((size_t)5*ar*GW*64*4) + al((size_t)3*xr*GW*64*4)
                   + winB + voxB + w1B + 2*w23B + al((size_t)ns*N*4) + 256;
        if (tot + (1<<16) <= ws_size) { NS = ns; break; }
    }
    int SH = 400/NS, AR = SH + 4, XR = SH + 2;

    char* ws = (char*)d_ws;
    size_t off = 0;
    auto alloc = [&](size_t bytes) -> void* {
        void* p = ws + off; off += al(bytes); return p;
    };
    size_t accB = (size_t)5*AR*GW*64*4;
    size_t actB = (size_t)3*XR*GW*64*4;
    float* accS   = (float*)alloc(accB);
    float* actS   = (float*)alloc(actB);
    int*   winner = (int*)alloc((size_t)10*GH*GW*4);
    float* voxw   = (float*)alloc((size_t)N*128*4);
    float* wt1    = (float*)alloc((size_t)27*128*64*4);
    float* wt2    = (float*)alloc((size_t)27*64*64*4);
    float* wt3    = (float*)alloc((size_t)27*64*64*4);
    int*   list   = (int*)alloc((size_t)NS*N*4);
    int*   cnt    = (int*)alloc(256);

    hipMemsetAsync(winner, 0xFF, (size_t)10*GH*GW*4, stream);
    hipMemsetAsync(cnt, 0, 256, stream);

    k_tr_w<<<(27*128*64 + 255)/256, 256, 0, stream>>>(wc1, wt1, 128, 64);
    k_tr_w<<<(27*64*64  + 255)/256, 256, 0, stream>>>(wc2, wt2, 64, 64);
    k_tr_w<<<(27*64*64  + 255)/256, 256, 0, stream>>>(wc3, wt3, 64, 64);

    k_winner<<<(N + 255)/256, 256, 0, stream>>>(coors, winner, N);
    k_lists<<<(N + 255)/256, 256, 0, stream>>>(coors, list, cnt, N, SH, NS);
    k_vfe<<<N, 128, 0, stream>>>(feats, nvox, w1, g1, b1, w2, g2, b2, wl, gl, bl, voxw);

    for (int s = 0; s < NS; ++s) {
        hipMemsetAsync(accS, 0, accB, stream);
        k_scat<<<(N + 31)/32, 256, 0, stream>>>(
            (const float4*)voxw, coors, winner, (const float4*)wt1,
            accS, list + (long)s*N, cnt + s, s*SH - 2, AR);
        // conv2: rows [s*SH-1, s*SH+SH+1); in accS (raw conv1 sums, fuse
        // bn1+relu on read), out actS (bn2+relu on write)
        k_conv<<<dim3(11, XR, 3), 256, 0, stream>>>(
            accS, s*SH - 2, (long)AR*GW*64,
            actS, s*SH - 1, 1L, (long)XR*GW*64, (long)GW*64, 64L,
            (const float4*)wt2, gc1, bc1, gc2, bc2,
            5, 1, 0, s*SH - 1);
        // conv3: rows [s*SH, (s+1)*SH); in actS (already activated),
        // out = d_out viewed [co*2+do][400][352]
        k_conv<<<dim3(11, SH, 2), 256, 0, stream>>>(
            actS, s*SH - 1, (long)XR*GW*64,
            (float*)d_out, 0, (long)2*GH*GW, (long)GH*GW, (long)GW, 1L,
            (const float4*)wt3, nullptr, nullptr, gc3, bc3,
            3, 2, 1, s*SH);
    }
}

// Round 3
// 3650.139 us; speedup vs baseline: 7.5561x; 7.5561x over previous
//
#include <hip/hip_runtime.h>
#include <hip/hip_bf16.h>

#define BNC 0.99950037f   // 1/sqrt(1+1e-3), BN eval scale factor
#define GH 400
#define GW 352

// ---------------------------------------------------------------------------
// Winner grid: last voxel index wins for duplicate cells (matches np fancy-set)
// ---------------------------------------------------------------------------
__global__ void k_winner(const int* __restrict__ coors, int* __restrict__ winner, int N) {
    int i = blockIdx.x * 256 + threadIdx.x;
    if (i >= N) return;
    int d = coors[i*4+1], h = coors[i*4+2], w = coors[i*4+3];
    atomicMax(&winner[(d*GH + h)*GW + w], i);
}

// ---------------------------------------------------------------------------
// Per-strip voxel lists (voxel row h touches conv1-out rows h-1..h+1; strip s
// consumes conv1 rows [s*SH-2, s*SH+SH+2))
// ---------------------------------------------------------------------------
__global__ void k_lists(const int* __restrict__ coors, int* __restrict__ list,
                        int* __restrict__ cnt, int N, int SH, int NS) {
    int i = blockIdx.x * 256 + threadIdx.x;
    if (i >= N) return;
    int h = coors[i*4+2];
    for (int s = 0; s < NS; ++s) {
        int lo = s*SH - 3, hi = s*SH + SH + 3;
        if (h >= lo && h < hi) {
            int p = atomicAdd(&cnt[s], 1);
            list[(long)s*N + p] = i;
        }
    }
}

// ---------------------------------------------------------------------------
// Weight transpose for conv1/scatter: OIDHW -> [tap][ci4][co][4]
// ---------------------------------------------------------------------------
__global__ void k_tr_w(const float* __restrict__ w, float* __restrict__ wt, int CI, int CO) {
    int idx = blockIdx.x * 256 + threadIdx.x;
    int total = 27 * CI * CO;
    if (idx >= total) return;
    int j   = idx & 3;
    int t1  = idx >> 2;
    int co  = t1 % CO;
    int t2  = t1 / CO;
    int ci4 = t2 % (CI/4);
    int tap = t2 / (CI/4);
    int ci  = ci4*4 + j;
    wt[idx] = w[(co*CI + ci)*27 + tap];
}

// Weight transpose for dense convs: OIDHW -> [tap][ci][co]
__global__ void k_tr_wg(const float* __restrict__ w, float* __restrict__ wt) {
    int idx = blockIdx.x * 256 + threadIdx.x;
    if (idx >= 27*64*64) return;
    int co  = idx & 63;
    int ci  = (idx >> 6) & 63;
    int tap = idx >> 12;
    wt[idx] = w[(co*64 + ci)*27 + tap];
}

// ---------------------------------------------------------------------------
// VFE: one block (128 thr) per voxel. Faithful-to-reference quirks:
// mean over ALL 35 rows / num_voxels; per-layer max over ALL rows pre-mask.
// ---------------------------------------------------------------------------
__global__ __launch_bounds__(128) void k_vfe(
    const float* __restrict__ feats, const int* __restrict__ nvox,
    const float* __restrict__ w1, const float* __restrict__ g1g, const float* __restrict__ b1g,
    const float* __restrict__ w2, const float* __restrict__ g2g, const float* __restrict__ b2g,
    const float* __restrict__ wlg, const float* __restrict__ glg, const float* __restrict__ blg,
    float* __restrict__ voxelwise)
{
    __shared__ float P[13320];
    float* X2    = P;          // [35][128]
    float* WL    = P + 4480;   // [128][33]
    float* AGG   = P + 8704;   // [128]
    float* MEANS = P + 8832;   // [3]
    float* B     = P + 8840;   // overlay region (4480 floats)
    float* F  = B;             // [35][8]
    float* W1 = B + 280;       // [16][8]
    float* G1 = B + 408, *B1 = B + 424;
    float* X1 = B + 440;       // [35][32]
    float* W2 = B + 1560;      // [64][33]
    float* G2 = B + 3672, *B2 = B + 3736;
    float* YL = B;             // [35][128] overlays in linear phase

    int tid = threadIdx.x;
    int vox = blockIdx.x;
    int nv  = nvox[vox];

    const float* fsrc = feats + (long)vox * 140;
    for (int idx = tid; idx < 140; idx += 128) { int t = idx>>2, c = idx&3; F[t*8+c] = fsrc[idx]; }
    if (tid < 112) { int u = tid/7, c = tid - u*7; W1[u*8+c] = w1[tid]; }
    if (tid < 16)  { G1[tid] = g1g[tid]; B1[tid] = b1g[tid]; }
    __syncthreads();

    if (tid < 3) {
        float s = 0.f;
        for (int t = 0; t < 35; ++t) s += F[t*8 + tid];
        MEANS[tid] = s / (float)nv;
    }
    __syncthreads();
    for (int idx = tid; idx < 105; idx += 128) { int t = idx/3, c = idx - t*3; F[t*8+4+c] = F[t*8+c] - MEANS[c]; }
    __syncthreads();

    for (int idx = tid; idx < 560; idx += 128) {
        int t = idx >> 4, u = idx & 15;
        float a = 0.f;
        #pragma unroll
        for (int c = 0; c < 7; ++c) a += F[t*8+c] * W1[u*8+c];
        X1[t*32+u] = fmaxf(a * (G1[u]*BNC) + B1[u], 0.f);
    }
    __syncthreads();
    if (tid < 16) {
        float m = 0.f;
        for (int t = 0; t < 35; ++t) m = fmaxf(m, X1[t*32+tid]);
        AGG[tid] = m;
    }
    __syncthreads();
    for (int idx = tid; idx < 1120; idx += 128) {
        int t = idx >> 5, j = idx & 31;
        bool v = t < nv;
        if (j < 16) { if (!v) X1[idx] = 0.f; }
        else        X1[idx] = v ? AGG[j-16] : 0.f;
    }
    for (int idx = tid; idx < 2048; idx += 128) { int u = idx>>5, c = idx&31; W2[u*33+c] = w2[idx]; }
    if (tid < 64) { G2[tid] = g2g[tid]; B2[tid] = b2g[tid]; }
    __syncthreads();

    if (tid < 64) {
        int u = tid;
        float su = G2[u]*BNC, bu = B2[u];
        for (int t = 0; t < 35; ++t) {
            float a = 0.f;
            #pragma unroll
            for (int c = 0; c < 32; ++c) a += X1[t*32+c] * W2[u*33+c];
            X2[t*128+u] = fmaxf(a*su + bu, 0.f);
        }
    }
    __syncthreads();
    if (tid < 64) {
        float m = 0.f;
        for (int t = 0; t < 35; ++t) m = fmaxf(m, X2[t*128+tid]);
        AGG[tid] = m;
    }
    __syncthreads();
    for (int idx = tid; idx < 4480; idx += 128) {
        int t = idx >> 7, j = idx & 127;
        bool v = t < nv;
        if (j < 64) { if (!v) X2[idx] = 0.f; }
        else        X2[idx] = v ? AGG[j-64] : 0.f;
    }
    __syncthreads();

    for (int c0 = 0; c0 < 128; c0 += 32) {
        for (int idx = tid; idx < 4096; idx += 128) {
            int u = idx >> 5, j = idx & 31;
            WL[u*33+j] = wlg[u*128 + c0 + j];
        }
        __syncthreads();
        {
            int u = tid;
            float wreg[32];
            #pragma unroll
            for (int j = 0; j < 32; ++j) wreg[j] = WL[u*33+j];
            for (int t = 0; t < 35; ++t) {
                const float4* xv = (const float4*)(X2 + t*128 + c0);
                float a = 0.f;
                #pragma unroll
                for (int q = 0; q < 8; ++q) {
                    float4 x4 = xv[q];
                    a += x4.x*wreg[q*4] + x4.y*wreg[q*4+1] + x4.z*wreg[q*4+2] + x4.w*wreg[q*4+3];
                }
                if (c0 == 0) YL[t*128+u] = a; else YL[t*128+u] += a;
            }
        }
        __syncthreads();
    }

    {
        int u = tid;
        float su = glg[u]*BNC, bu = blg[u];
        float m = 0.f;
        for (int t = 0; t < nv; ++t) m = fmaxf(m, fmaxf(YL[t*128+u]*su + bu, 0.f));
        voxelwise[(long)vox*128 + u] = m;
    }
}

// ---------------------------------------------------------------------------
// conv1 as sparse scatter into one H-strip's accumulator.
// accS layout: [5][AR][352][64], row r <-> global conv1-out row h_lo + r.
// ---------------------------------------------------------------------------
__global__ __launch_bounds__(256) void k_scat(
    const float4* __restrict__ voxf4, const int* __restrict__ coors,
    const int* __restrict__ winner, const float4* __restrict__ Wt1,
    float* __restrict__ accS, const int* __restrict__ list,
    const int* __restrict__ cnt, int h_lo, int AR)
{
    __shared__ float4 sW[2048];     // [ci4=32][co=64]  32KB
    __shared__ float4 sF[32][32];   // 32 voxels x 128ch 16KB
    __shared__ int sI[32], sD[32], sH_[32], sWc[32], sV[32];
    int tid = threadIdx.x;
    int cn = cnt[0];
    int v0 = blockIdx.x * 32;
    if (v0 >= cn) return;

    if (tid < 32) {
        int slot = v0 + tid;
        int i = -1, d = 0, h = 0, w = 0, ok = 0;
        if (slot < cn) {
            i = list[slot];
            d = coors[i*4+1]; h = coors[i*4+2]; w = coors[i*4+3];
            ok = (winner[(d*GH + h)*GW + w] == i);
        }
        sI[tid] = i; sD[tid] = d; sH_[tid] = h; sWc[tid] = w; sV[tid] = ok;
    }
    __syncthreads();
    for (int idx = tid; idx < 1024; idx += 256) {
        int v = idx >> 5, c = idx & 31;
        int vi = sI[v];
        if (vi >= 0) sF[v][c] = voxf4[(long)vi*32 + c];
    }

    int co = tid & 63, wv = tid >> 6;
    for (int tap = 0; tap < 27; ++tap) {
        __syncthreads();
        for (int idx = tid; idx < 2048; idx += 256) sW[idx] = Wt1[tap*2048 + idx];
        __syncthreads();
        int kd = tap/9, kh = (tap/3)%3, kw = tap%3;
        for (int s8 = 0; s8 < 8; ++s8) {
            int v = wv*8 + s8;                 // wave-uniform
            int od2 = sD[v] + 1 - kd;
            int oh  = sH_[v] + 1 - kh;
            int ow  = sWc[v] + 1 - kw;
            bool ok = sV[v] && !(od2 & 1) && (unsigned)od2 < 10u
                      && oh >= 0 && oh < GH && oh >= h_lo && oh < h_lo + AR
                      && (unsigned)ow < (unsigned)GW;
            if (ok) {
                float a = 0.f;
                #pragma unroll
                for (int c4 = 0; c4 < 32; ++c4) {
                    float4 wq = sW[c4*64 + co];
                    float4 f4 = sF[v][c4];
                    a += f4.x*wq.x + f4.y*wq.y + f4.z*wq.z + f4.w*wq.w;
                }
                long cell = (long)((od2>>1)*AR + (oh - h_lo))*GW + ow;
                atomicAdd(&accS[cell*64 + co], a);
            }
        }
    }
}

// ---------------------------------------------------------------------------
// Dense conv3d, implicit-GEMM register tiling.
// Block tile: 120 w x 64 co x 2 oh x 1 od; thread: 8 w x 8 co (acc[8][8]).
// Input staged TRANSPOSED in LDS [os][ci][L] (L = w-w0+1, stride 124);
// weights read straight from global wt[tap][ci][co] (L2-resident, VMEM pipe).
// Fused bn+relu of previous layer on stage (gin nullable), bn+relu on output.
// Output goes through an LDS transpose for coalesced stores in either
// channels-last (sW==64) or co-major (sW==1) destination layouts.
// ---------------------------------------------------------------------------
__global__ __launch_bounds__(256) void k_conv(
    const float* __restrict__ src, int src_h0, long src_dpitch,
    float* __restrict__ dst, int dst_h0, long sC, long sD, long sH, long sW,
    const float* __restrict__ wt,
    const float* __restrict__ gin, const float* __restrict__ bin,
    const float* __restrict__ gout, const float* __restrict__ bout,
    int D_in, int d_stride, int d_pad, int y0, int nrows)
{
    __shared__ __align__(16) char smem[64000];
    float (*sIn)[64][124] = (float (*)[64][124])smem;   // 63488 B
    float* sAct = (float*)(smem + 63488);               // 2x64 floats
    float* sOut = (float*)smem;                         // reused after compute

    int t  = threadIdx.x;
    int wl = t & 15;            // wl==15 idle in compute (tile = 15*8 = 120 w)
    int cg = (t >> 4) & 7;
    int os = t >> 7;
    int w0 = blockIdx.x * 120;
    int by = blockIdx.y;
    int od = blockIdx.z;
    bool hasact = (gin != nullptr);
    if (t < 64)  sAct[t]    = hasact ? gin[t]*BNC : 1.f;
    else if (t < 128) sAct[t] = hasact ? bin[t-64] : 0.f;

    float acc[8][8];
    #pragma unroll
    for (int j = 0; j < 8; ++j)
        #pragma unroll
        for (int c = 0; c < 8; ++c) acc[j][c] = 0.f;

    for (int kd = 0; kd < 3; ++kd) {
        int dp = od*d_stride + kd - d_pad;
        if (dp < 0 || dp >= D_in) continue;            // uniform
        for (int kh = 0; kh < 3; ++kh) {
            __syncthreads();                           // protect prior LDS reads
            // ---- stage 2 rows x 122 w x 64 ci, transposed, bn+relu fused ----
            {
                const float* sbase = src + dp*src_dpitch;
                for (int f = t; f < 2*122*16; f += 256) {
                    int ci4  = f & 15;
                    int rem  = f >> 4;
                    int wloc = rem % 122;
                    int os2  = rem / 122;
                    int hp = y0 + by*2 + os2 + kh - 1;
                    int w  = w0 - 1 + wloc;
                    float4 v = make_float4(0.f, 0.f, 0.f, 0.f);
                    if ((unsigned)hp < (unsigned)GH && (unsigned)w < (unsigned)GW) {
                        v = *(const float4*)(sbase + ((long)(hp - src_h0)*GW + w)*64 + ci4*4);
                        v.x = fmaxf(v.x*sAct[ci4*4+0] + sAct[64+ci4*4+0], 0.f);
                        v.y = fmaxf(v.y*sAct[ci4*4+1] + sAct[64+ci4*4+1], 0.f);
                        v.z = fmaxf(v.z*sAct[ci4*4+2] + sAct[64+ci4*4+2], 0.f);
                        v.w = fmaxf(v.w*sAct[ci4*4+3] + sAct[64+ci4*4+3], 0.f);
                    }
                    float* col = &sIn[os2][ci4*4][wloc];
                    col[0]   = v.x;
                    col[124] = v.y;
                    col[248] = v.z;
                    col[372] = v.w;
                }
            }
            __syncthreads();
            // ---- inner: per ci, 3 LDS b128 (input window) + 6 global f4 (w) ----
            const float* wbase = wt + ((kd*3 + kh)*3) * 4096 + cg*8;
            #pragma unroll 2
            for (int ci = 0; ci < 64; ++ci) {
                const float* ip = &sIn[os][ci][wl*8];
                float4 A0 = *(const float4*)(ip);
                float4 A1 = *(const float4*)(ip + 4);
                float4 A2 = *(const float4*)(ip + 8);
                float win[12] = {A0.x,A0.y,A0.z,A0.w, A1.x,A1.y,A1.z,A1.w,
                                 A2.x,A2.y,A2.z,A2.w};
                #pragma unroll
                for (int kw = 0; kw < 3; ++kw) {
                    const float4* wp = (const float4*)(wbase + (kw<<12) + (ci<<6));
                    float4 B0 = wp[0], B1 = wp[1];
                    #pragma unroll
                    for (int j = 0; j < 8; ++j) {
                        float av = win[j + kw];
                        acc[j][0] = fmaf(av, B0.x, acc[j][0]);
                        acc[j][1] = fmaf(av, B0.y, acc[j][1]);
                        acc[j][2] = fmaf(av, B0.z, acc[j][2]);
                        acc[j][3] = fmaf(av, B0.w, acc[j][3]);
                        acc[j][4] = fmaf(av, B1.x, acc[j][4]);
                        acc[j][5] = fmaf(av, B1.y, acc[j][5]);
                        acc[j][6] = fmaf(av, B1.z, acc[j][6]);
                        acc[j][7] = fmaf(av, B1.w, acc[j][7]);
                    }
                }
            }
        }
    }

    // ---- epilogue: bn+relu, LDS transpose, coalesced store ----
    float so[8], bo[8];
    #pragma unroll
    for (int c = 0; c < 8; ++c) { so[c] = gout[cg*8+c]*BNC; bo[c] = bout[cg*8+c]; }
    __syncthreads();                                   // done reading sIn
    bool comajor = (sW == 1);
    if (wl < 15) {
        #pragma unroll
        for (int j = 0; j < 8; ++j)
            #pragma unroll
            for (int c = 0; c < 8; ++c) {
                float r = fmaxf(acc[j][c]*so[c] + bo[c], 0.f);
                if (comajor) sOut[(os*64 + cg*8+c)*120 + wl*8 + j] = r;
                else         sOut[(os*120 + wl*8+j)*64 + cg*8 + c] = r;
            }
    }
    __syncthreads();
    if (comajor) {
        // rows = (os,co) pairs: 128 rows x 30 float4
        for (int f = t; f < 128*30; f += 256) {
            int q  = f % 30, r = f / 30;
            int os2 = r >> 6, co = r & 63;
            int row = y0 + by*2 + os2;
            int w   = w0 + q*4;
            if (by*2 + os2 < nrows && (unsigned)row < (unsigned)GH && w < GW) {
                float4 v = *(const float4*)&sOut[(os2*64 + co)*120 + q*4];
                *(float4*)&dst[(long)co*sC + (long)od*sD + (long)(row - dst_h0)*sH + w] = v;
            }
        }
    } else {
        for (int f = t; f < 2*120*16; f += 256) {
            int ci4 = f & 15;
            int rem = f >> 4;
            int w   = rem % 120;
            int os2 = rem / 120;
            int row = y0 + by*2 + os2;
            int ww  = w0 + w;
            if (by*2 + os2 < nrows && (unsigned)row < (unsigned)GH && ww < GW) {
                float4 v = *(const float4*)&sOut[(os2*120 + w)*64 + ci4*4];
                *(float4*)&dst[(long)od*sD + (long)(row - dst_h0)*sH + (long)ww*64 + ci4*4] = v;
            }
        }
    }
}

// ---------------------------------------------------------------------------
extern "C" void kernel_launch(void* const* d_in, const int* in_sizes, int n_in,
                              void* d_out, int out_size, void* d_ws, size_t ws_size,
                              hipStream_t stream)
{
    const float* feats = (const float*)d_in[0];
    const int*   nvox  = (const int*)d_in[1];
    const int*   coors = (const int*)d_in[2];
    const float* w1  = (const float*)d_in[4];
    const float* g1  = (const float*)d_in[5];
    const float* b1  = (const float*)d_in[6];
    const float* w2  = (const float*)d_in[7];
    const float* g2  = (const float*)d_in[8];
    const float* b2  = (const float*)d_in[9];
    const float* wl  = (const float*)d_in[10];
    const float* gl  = (const float*)d_in[11];
    const float* bl  = (const float*)d_in[12];
    const float* wc1 = (const float*)d_in[13];
    const float* gc1 = (const float*)d_in[14];
    const float* bc1 = (const float*)d_in[15];
    const float* wc2 = (const float*)d_in[16];
    const float* gc2 = (const float*)d_in[17];
    const float* bc2 = (const float*)d_in[18];
    const float* wc3 = (const float*)d_in[19];
    const float* gc3 = (const float*)d_in[20];
    const float* bc3 = (const float*)d_in[21];

    int N = in_sizes[1];            // 20000 voxels

    auto al = [](size_t b) { return (b + 255) & ~(size_t)255; };

    // --- choose strip count NS: smallest NS whose workspace fits ws_size ---
    size_t winB = al((size_t)10*GH*GW*4);
    size_t voxB = al((size_t)N*128*4);
    size_t w1B  = al((size_t)27*128*64*4);
    size_t w23B = al((size_t)27*64*64*4);
    int NS = 16;
    const int cand[5] = {1, 2, 4, 8, 16};
    for (int k = 0; k < 5; ++k) {
        int ns = cand[k], sh = 400/ns, ar = sh + 4, xr = sh + 2;
        size_t tot = al((size_t)5*ar*GW*64*4) + al((size_t)3*xr*GW*64*4)
                   + winB + voxB + w1B + 2*w23B + al((size_t)ns*N*4) + 256;
        if (tot + (1<<16) <= ws_size) { NS = ns; break; }
    }
    int SH = 400/NS, AR = SH + 4, XR = SH + 2;

    char* ws = (char*)d_ws;
    size_t off = 0;
    auto alloc = [&](size_t bytes) -> void* {
        void* p = ws + off; off += al(bytes); return p;
    };
    size_t accB = (size_t)5*AR*GW*64*4;
    size_t actB = (size_t)3*XR*GW*64*4;
    float* accS   = (float*)alloc(accB);
    float* actS   = (float*)alloc(actB);
    int*   winner = (int*)alloc((size_t)10*GH*GW*4);
    float* voxw   = (float*)alloc((size_t)N*128*4);
    float* wt1    = (float*)alloc((size_t)27*128*64*4);
    float* wt2    = (float*)alloc((size_t)27*64*64*4);
    float* wt3    = (float*)alloc((size_t)27*64*64*4);
    int*   list   = (int*)alloc((size_t)NS*N*4);
    int*   cnt    = (int*)alloc(256);

    hipMemsetAsync(winner, 0xFF, (size_t)10*GH*GW*4, stream);
    hipMemsetAsync(cnt, 0, 256, stream);

    k_tr_w<<<(27*128*64 + 255)/256, 256, 0, stream>>>(wc1, wt1, 128, 64);
    k_tr_wg<<<(27*64*64 + 255)/256, 256, 0, stream>>>(wc2, wt2);
    k_tr_wg<<<(27*64*64 + 255)/256, 256, 0, stream>>>(wc3, wt3);

    k_winner<<<(N + 255)/256, 256, 0, stream>>>(coors, winner, N);
    k_lists<<<(N + 255)/256, 256, 0, stream>>>(coors, list, cnt, N, SH, NS);
    k_vfe<<<N, 128, 0, stream>>>(feats, nvox, w1, g1, b1, w2, g2, b2, wl, gl, bl, voxw);

    for (int s = 0; s < NS; ++s) {
        hipMemsetAsync(accS, 0, accB, stream);
        k_scat<<<(N + 31)/32, 256, 0, stream>>>(
            (const float4*)voxw, coors, winner, (const float4*)wt1,
            accS, list + (long)s*N, cnt + s, s*SH - 2, AR);
        // conv2: out rows [s*SH-1, s*SH+SH+1); src accS raw (fuse bn1+relu),
        // dst actS channels-last (sW=64), bn2+relu on write
        k_conv<<<dim3(3, (SH+2+1)/2, 3), 256, 0, stream>>>(
            accS, s*SH - 2, (long)AR*GW*64,
            actS, s*SH - 1, 1L, (long)XR*GW*64, (long)GW*64, 64L,
            wt2, gc1, bc1, gc2, bc2,
            5, 1, 0, s*SH - 1, SH + 2);
        // conv3: out rows [s*SH, (s+1)*SH); src actS activated; dst d_out
        // co-major (sW=1), channel = co*2 + od
        k_conv<<<dim3(3, (SH+1)/2, 2), 256, 0, stream>>>(
            actS, s*SH - 1, (long)XR*GW*64,
            (float*)d_out, 0, (long)2*GH*GW, (long)GH*GW, (long)GW, 1L,
            wt3, nullptr, nullptr, gc3, bc3,
            3, 2, 1, s*SH, SH);
    }
}

// Round 4
// 3127.854 us; speedup vs baseline: 8.8178x; 1.1670x over previous
//
#include <hip/hip_runtime.h>
#include <hip/hip_bf16.h>

#define BNC 0.99950037f   // 1/sqrt(1+1e-3), BN eval scale factor
#define GH 400
#define GW 352

// ---------------------------------------------------------------------------
// Winner grid: last voxel index wins for duplicate cells (matches np fancy-set)
// ---------------------------------------------------------------------------
__global__ void k_winner(const int* __restrict__ coors, int* __restrict__ winner, int N) {
    int i = blockIdx.x * 256 + threadIdx.x;
    if (i >= N) return;
    int d = coors[i*4+1], h = coors[i*4+2], w = coors[i*4+3];
    atomicMax(&winner[(d*GH + h)*GW + w], i);
}

// ---------------------------------------------------------------------------
// Per-strip voxel lists (voxel row h touches conv1-out rows h-1..h+1; strip s
// consumes conv1 rows [s*SH-2, s*SH+SH+2))
// ---------------------------------------------------------------------------
__global__ void k_lists(const int* __restrict__ coors, int* __restrict__ list,
                        int* __restrict__ cnt, int N, int SH, int NS) {
    int i = blockIdx.x * 256 + threadIdx.x;
    if (i >= N) return;
    int h = coors[i*4+2];
    for (int s = 0; s < NS; ++s) {
        int lo = s*SH - 3, hi = s*SH + SH + 3;
        if (h >= lo && h < hi) {
            int p = atomicAdd(&cnt[s], 1);
            list[(long)s*N + p] = i;
        }
    }
}

// ---------------------------------------------------------------------------
// Weight transpose for conv1/scatter: OIDHW -> [tap][ci4][co][4]
// ---------------------------------------------------------------------------
__global__ void k_tr_w(const float* __restrict__ w, float* __restrict__ wt, int CI, int CO) {
    int idx = blockIdx.x * 256 + threadIdx.x;
    int total = 27 * CI * CO;
    if (idx >= total) return;
    int j   = idx & 3;
    int t1  = idx >> 2;
    int co  = t1 % CO;
    int t2  = t1 / CO;
    int ci4 = t2 % (CI/4);
    int tap = t2 / (CI/4);
    int ci  = ci4*4 + j;
    wt[idx] = w[(co*CI + ci)*27 + tap];
}

// Weight transpose for dense convs: OIDHW -> [tap][ci][co]
__global__ void k_tr_wg(const float* __restrict__ w, float* __restrict__ wt) {
    int idx = blockIdx.x * 256 + threadIdx.x;
    if (idx >= 27*64*64) return;
    int co  = idx & 63;
    int ci  = (idx >> 6) & 63;
    int tap = idx >> 12;
    wt[idx] = w[(co*64 + ci)*27 + tap];
}

// Linear-layer weight transpose: wl[u][c] -> WT[c][u]
__global__ void k_tr_lin(const float* __restrict__ wl, float* __restrict__ WT) {
    int idx = blockIdx.x * 256 + threadIdx.x;
    if (idx >= 16384) return;
    int u = idx & 127, c = idx >> 7;
    WT[c*128 + u] = wl[u*128 + c];
}

// ---------------------------------------------------------------------------
// VFE: one block (128 thr) per voxel. Faithful-to-reference quirks:
// mean over ALL 35 rows / num_voxels; layer1 agg over ALL 35 (unmasked) rows;
// layer2 agg = max(rows t<nv, relu(b2) if nv<35) since masked rows are zero.
// Linear phase register-tiled 8u x 5t, weights from global (WT, L2-hot).
// ---------------------------------------------------------------------------
__global__ __launch_bounds__(128) void k_vfe(
    const float* __restrict__ feats, const int* __restrict__ nvox,
    const float* __restrict__ w1, const float* __restrict__ g1g, const float* __restrict__ b1g,
    const float* __restrict__ w2g, const float* __restrict__ g2g, const float* __restrict__ b2g,
    const float* __restrict__ WT, const float* __restrict__ glg, const float* __restrict__ blg,
    float* __restrict__ voxelwise)
{
    __shared__ float F[35*8];        // cols 0..3 feat, 4..6 rel, 7 zero
    __shared__ float W1s[16*8];      // col 7 zero
    __shared__ float SG1[16], SB1[16];
    __shared__ float X1[35*36];      // stride 36 (9 float4)
    __shared__ float X2[35*132];     // stride 132 (33 float4)
    __shared__ float RED[8*128];     // layer2: [2][64]; linear: [8][128]
    __shared__ float AGG1[16];
    __shared__ float AGG2[64];
    __shared__ float MEANS[3];

    int tid = threadIdx.x;
    int vox = blockIdx.x;
    int nv  = nvox[vox];

    const float* fsrc = feats + (long)vox * 140;
    for (int idx = tid; idx < 140; idx += 128) { int t = idx>>2, c = idx&3; F[t*8+c] = fsrc[idx]; }
    if (tid < 35) F[tid*8+7] = 0.f;
    if (tid < 112) { int u = tid/7, c = tid - u*7; W1s[u*8+c] = w1[tid]; }
    if (tid < 16)  { W1s[tid*8+7] = 0.f; SG1[tid] = g1g[tid]*BNC; SB1[tid] = b1g[tid]; }
    __syncthreads();

    if (tid < 3) {
        float s = 0.f;
        for (int t = 0; t < 35; ++t) s += F[t*8 + tid];
        MEANS[tid] = s / (float)nv;
    }
    __syncthreads();
    for (int idx = tid; idx < 105; idx += 128) { int t = idx/3, c = idx - t*3; F[t*8+4+c] = F[t*8+c] - MEANS[c]; }
    __syncthreads();

    // ---- layer1: all 35 rows (agg1 must see unmasked garbage rows) ----
    {
        const float4* Ff4  = (const float4*)F;
        const float4* W1f4 = (const float4*)W1s;
        for (int idx = tid; idx < 560; idx += 128) {
            int t = idx >> 4, u = idx & 15;
            float4 a0 = Ff4[t*2], a1 = Ff4[t*2+1];
            float4 b0 = W1f4[u*2], b1v = W1f4[u*2+1];
            float a = a0.x*b0.x + a0.y*b0.y + a0.z*b0.z + a0.w*b0.w
                    + a1.x*b1v.x + a1.y*b1v.y + a1.z*b1v.z + a1.w*b1v.w;
            X1[t*36+u] = fmaxf(a*SG1[u] + SB1[u], 0.f);
        }
    }
    __syncthreads();
    if (tid < 16) {
        float m = 0.f;
        for (int t = 0; t < 35; ++t) m = fmaxf(m, X1[t*36+tid]);
        AGG1[tid] = m;
    }
    __syncthreads();
    {   // agg cols only for rows t<nv (only those feed layer2)
        float4* X1f4 = (float4*)X1;
        const float4* A1f4 = (const float4*)AGG1;
        for (int idx = tid; idx < nv*4; idx += 128) {
            int t = idx >> 2, k = idx & 3;
            X1f4[t*9 + 4 + k] = A1f4[k];
        }
    }
    __syncthreads();

    // ---- layer2: all 128 threads, weights in registers ----
    {
        int u = tid & 63, tg = tid >> 6;
        float w2r[32];
        const float4* wsrc = (const float4*)(w2g + u*32);
        #pragma unroll
        for (int q = 0; q < 8; ++q) {
            float4 w4 = wsrc[q];
            w2r[q*4] = w4.x; w2r[q*4+1] = w4.y; w2r[q*4+2] = w4.z; w2r[q*4+3] = w4.w;
        }
        float su = g2g[u]*BNC, bu = b2g[u];
        float lm = (nv < 35) ? fmaxf(bu, 0.f) : 0.f;   // zero-row contribution
        for (int t = tg; t < nv; t += 2) {
            const float4* xr = (const float4*)(X1 + t*36);
            float a = 0.f;
            #pragma unroll
            for (int q = 0; q < 8; ++q) {
                float4 x4 = xr[q];
                a += x4.x*w2r[q*4] + x4.y*w2r[q*4+1] + x4.z*w2r[q*4+2] + x4.w*w2r[q*4+3];
            }
            float h = fmaxf(a*su + bu, 0.f);
            X2[t*132 + u] = h;
            lm = fmaxf(lm, h);
        }
        RED[tg*64 + u] = lm;
    }
    __syncthreads();
    if (tid < 64) AGG2[tid] = fmaxf(RED[tid], RED[64+tid]);
    __syncthreads();
    {
        float4* X2f4 = (float4*)X2;
        const float4* A2f4 = (const float4*)AGG2;
        for (int idx = tid; idx < nv*16; idx += 128) {
            int t = idx >> 4, k = idx & 15;
            X2f4[t*33 + 16 + k] = A2f4[k];
        }
    }
    __syncthreads();

    // ---- linear 128x128 over rows t<nv: thread = (tg4 0..7) x (ug 0..15) ----
    {
        int ug = tid & 15, tg4 = tid >> 4;
        int u0 = ug * 8;
        int kmax = (nv > tg4) ? ((nv - tg4 + 7) >> 3) : 0;
        float acc[5][8];
        #pragma unroll
        for (int k = 0; k < 5; ++k)
            #pragma unroll
            for (int j = 0; j < 8; ++j) acc[k][j] = 0.f;

        const float4* X2f4 = (const float4*)X2;
        const float4* WTf4 = (const float4*)WT;
        for (int c4 = 0; c4 < 32; ++c4) {
            float4 wv[8];
            #pragma unroll
            for (int cc = 0; cc < 4; ++cc) {
                wv[cc*2]   = WTf4[(c4*4+cc)*32 + ug*2];
                wv[cc*2+1] = WTf4[(c4*4+cc)*32 + ug*2 + 1];
            }
            #pragma unroll
            for (int k = 0; k < 5; ++k) {
                if (k < kmax) {
                    int t = tg4 + (k << 3);
                    float4 x4 = X2f4[t*33 + c4];
                    #pragma unroll
                    for (int cc = 0; cc < 4; ++cc) {
                        float xs = (cc == 0) ? x4.x : (cc == 1) ? x4.y : (cc == 2) ? x4.z : x4.w;
                        acc[k][0] = fmaf(xs, wv[cc*2].x,   acc[k][0]);
                        acc[k][1] = fmaf(xs, wv[cc*2].y,   acc[k][1]);
                        acc[k][2] = fmaf(xs, wv[cc*2].z,   acc[k][2]);
                        acc[k][3] = fmaf(xs, wv[cc*2].w,   acc[k][3]);
                        acc[k][4] = fmaf(xs, wv[cc*2+1].x, acc[k][4]);
                        acc[k][5] = fmaf(xs, wv[cc*2+1].y, acc[k][5]);
                        acc[k][6] = fmaf(xs, wv[cc*2+1].z, acc[k][6]);
                        acc[k][7] = fmaf(xs, wv[cc*2+1].w, acc[k][7]);
                    }
                }
            }
        }
        // bn+relu+max over this thread's rows
        float4 g0 = *(const float4*)(glg + u0), g1v = *(const float4*)(glg + u0 + 4);
        float4 b0 = *(const float4*)(blg + u0), b1v = *(const float4*)(blg + u0 + 4);
        float sg[8] = {g0.x*BNC, g0.y*BNC, g0.z*BNC, g0.w*BNC,
                       g1v.x*BNC, g1v.y*BNC, g1v.z*BNC, g1v.w*BNC};
        float sb[8] = {b0.x, b0.y, b0.z, b0.w, b1v.x, b1v.y, b1v.z, b1v.w};
        float m[8];
        #pragma unroll
        for (int j = 0; j < 8; ++j) m[j] = 0.f;
        #pragma unroll
        for (int k = 0; k < 5; ++k) {
            if (k < kmax) {
                #pragma unroll
                for (int j = 0; j < 8; ++j)
                    m[j] = fmaxf(m[j], fmaxf(acc[k][j]*sg[j] + sb[j], 0.f));
            }
        }
        #pragma unroll
        for (int j = 0; j < 8; ++j) RED[tg4*128 + u0 + j] = m[j];
    }
    __syncthreads();
    {
        float m = RED[tid];
        #pragma unroll
        for (int r = 1; r < 8; ++r) m = fmaxf(m, RED[r*128 + tid]);
        voxelwise[(long)vox*128 + tid] = m;
    }
}

// ---------------------------------------------------------------------------
// conv1 as sparse scatter into one H-strip's accumulator.
// Weights read from global (L2-hot); per-voxel tap validity hoisted
// (wave-uniform) so invalid taps skip the 128-ch dot entirely.
// accS layout: [5][AR][352][64], row r <-> global conv1-out row h_lo + r.
// ---------------------------------------------------------------------------
__global__ __launch_bounds__(256) void k_scat(
    const float4* __restrict__ voxf4, const int* __restrict__ coors,
    const int* __restrict__ winner, const float4* __restrict__ Wt1,
    float* __restrict__ accS, const int* __restrict__ list,
    const int* __restrict__ cnt, int h_lo, int AR)
{
    __shared__ float4 sF[32][32];   // 32 voxels x 128ch  16KB
    __shared__ int sI[32], sD[32], sH_[32], sWc[32], sV[32];
    int tid = threadIdx.x;
    int cn = cnt[0];
    int v0 = blockIdx.x * 32;
    if (v0 >= cn) return;

    if (tid < 32) {
        int slot = v0 + tid;
        int i = -1, d = 0, h = 0, w = 0, ok = 0;
        if (slot < cn) {
            i = list[slot];
            d = coors[i*4+1]; h = coors[i*4+2]; w = coors[i*4+3];
            ok = (winner[(d*GH + h)*GW + w] == i);
        }
        sI[tid] = i; sD[tid] = d; sH_[tid] = h; sWc[tid] = w; sV[tid] = ok;
    }
    __syncthreads();
    for (int idx = tid; idx < 1024; idx += 256) {
        int v = idx >> 5, c = idx & 31;
        int vi = sI[v];
        if (vi >= 0) sF[v][c] = voxf4[(long)vi*32 + c];
    }
    __syncthreads();

    int co = tid & 63, wv = tid >> 6;
    for (int tap = 0; tap < 27; ++tap) {
        int kd = tap/9, kh = (tap/3)%3, kw = tap%3;
        // per-voxel validity + cell (wave-uniform: depends only on v)
        bool okv[8]; long cell[8];
        #pragma unroll
        for (int s8 = 0; s8 < 8; ++s8) {
            int v = wv*8 + s8;
            int od2 = sD[v] + 1 - kd;
            int oh  = sH_[v] + 1 - kh;
            int ow  = sWc[v] + 1 - kw;
            okv[s8] = sV[v] && !(od2 & 1) && (unsigned)od2 < 10u
                      && oh >= 0 && oh < GH && oh >= h_lo && oh < h_lo + AR
                      && (unsigned)ow < (unsigned)GW;
            cell[s8] = okv[s8] ? ((long)((od2>>1)*AR + (oh - h_lo))*GW + ow) : 0;
        }
        float acc[8];
        #pragma unroll
        for (int s8 = 0; s8 < 8; ++s8) acc[s8] = 0.f;
        const float4* wbase = Wt1 + (long)tap*2048 + co;
        for (int c4 = 0; c4 < 32; ++c4) {
            float4 wq = wbase[c4*64];
            #pragma unroll
            for (int s8 = 0; s8 < 8; ++s8) {
                if (okv[s8]) {   // uniform at runtime within the wave
                    float4 f4 = sF[wv*8 + s8][c4];
                    acc[s8] += f4.x*wq.x + f4.y*wq.y + f4.z*wq.z + f4.w*wq.w;
                }
            }
        }
        #pragma unroll
        for (int s8 = 0; s8 < 8; ++s8) {
            if (okv[s8]) atomicAdd(&accS[cell[s8]*64 + co], acc[s8]);
        }
    }
}

// ---------------------------------------------------------------------------
// Dense conv3d, implicit-GEMM register tiling (unchanged from round 3).
// ---------------------------------------------------------------------------
__global__ __launch_bounds__(256) void k_conv(
    const float* __restrict__ src, int src_h0, long src_dpitch,
    float* __restrict__ dst, int dst_h0, long sC, long sD, long sH, long sW,
    const float* __restrict__ wt,
    const float* __restrict__ gin, const float* __restrict__ bin,
    const float* __restrict__ gout, const float* __restrict__ bout,
    int D_in, int d_stride, int d_pad, int y0, int nrows)
{
    __shared__ __align__(16) char smem[64000];
    float (*sIn)[64][124] = (float (*)[64][124])smem;   // 63488 B
    float* sAct = (float*)(smem + 63488);               // 2x64 floats
    float* sOut = (float*)smem;                         // reused after compute

    int t  = threadIdx.x;
    int wl = t & 15;            // wl==15 idle in compute (tile = 15*8 = 120 w)
    int cg = (t >> 4) & 7;
    int os = t >> 7;
    int w0 = blockIdx.x * 120;
    int by = blockIdx.y;
    int od = blockIdx.z;
    bool hasact = (gin != nullptr);
    if (t < 64)  sAct[t]    = hasact ? gin[t]*BNC : 1.f;
    else if (t < 128) sAct[t] = hasact ? bin[t-64] : 0.f;

    float acc[8][8];
    #pragma unroll
    for (int j = 0; j < 8; ++j)
        #pragma unroll
        for (int c = 0; c < 8; ++c) acc[j][c] = 0.f;

    for (int kd = 0; kd < 3; ++kd) {
        int dp = od*d_stride + kd - d_pad;
        if (dp < 0 || dp >= D_in) continue;            // uniform
        for (int kh = 0; kh < 3; ++kh) {
            __syncthreads();                           // protect prior LDS reads
            {
                const float* sbase = src + dp*src_dpitch;
                for (int f = t; f < 2*122*16; f += 256) {
                    int ci4  = f & 15;
                    int rem  = f >> 4;
                    int wloc = rem % 122;
                    int os2  = rem / 122;
                    int hp = y0 + by*2 + os2 + kh - 1;
                    int w  = w0 - 1 + wloc;
                    float4 v = make_float4(0.f, 0.f, 0.f, 0.f);
                    if ((unsigned)hp < (unsigned)GH && (unsigned)w < (unsigned)GW) {
                        v = *(const float4*)(sbase + ((long)(hp - src_h0)*GW + w)*64 + ci4*4);
                        v.x = fmaxf(v.x*sAct[ci4*4+0] + sAct[64+ci4*4+0], 0.f);
                        v.y = fmaxf(v.y*sAct[ci4*4+1] + sAct[64+ci4*4+1], 0.f);
                        v.z = fmaxf(v.z*sAct[ci4*4+2] + sAct[64+ci4*4+2], 0.f);
                        v.w = fmaxf(v.w*sAct[ci4*4+3] + sAct[64+ci4*4+3], 0.f);
                    }
                    float* col = &sIn[os2][ci4*4][wloc];
                    col[0]   = v.x;
                    col[124] = v.y;
                    col[248] = v.z;
                    col[372] = v.w;
                }
            }
            __syncthreads();
            const float* wbase = wt + ((kd*3 + kh)*3) * 4096 + cg*8;
            #pragma unroll 2
            for (int ci = 0; ci < 64; ++ci) {
                const float* ip = &sIn[os][ci][wl*8];
                float4 A0 = *(const float4*)(ip);
                float4 A1 = *(const float4*)(ip + 4);
                float4 A2 = *(const float4*)(ip + 8);
                float win[12] = {A0.x,A0.y,A0.z,A0.w, A1.x,A1.y,A1.z,A1.w,
                                 A2.x,A2.y,A2.z,A2.w};
                #pragma unroll
                for (int kw = 0; kw < 3; ++kw) {
                    const float4* wp = (const float4*)(wbase + (kw<<12) + (ci<<6));
                    float4 B0 = wp[0], B1 = wp[1];
                    #pragma unroll
                    for (int j = 0; j < 8; ++j) {
                        float av = win[j + kw];
                        acc[j][0] = fmaf(av, B0.x, acc[j][0]);
                        acc[j][1] = fmaf(av, B0.y, acc[j][1]);
                        acc[j][2] = fmaf(av, B0.z, acc[j][2]);
                        acc[j][3] = fmaf(av, B0.w, acc[j][3]);
                        acc[j][4] = fmaf(av, B1.x, acc[j][4]);
                        acc[j][5] = fmaf(av, B1.y, acc[j][5]);
                        acc[j][6] = fmaf(av, B1.z, acc[j][6]);
                        acc[j][7] = fmaf(av, B1.w, acc[j][7]);
                    }
                }
            }
        }
    }

    float so[8], bo[8];
    #pragma unroll
    for (int c = 0; c < 8; ++c) { so[c] = gout[cg*8+c]*BNC; bo[c] = bout[cg*8+c]; }
    __syncthreads();
    bool comajor = (sW == 1);
    if (wl < 15) {
        #pragma unroll
        for (int j = 0; j < 8; ++j)
            #pragma unroll
            for (int c = 0; c < 8; ++c) {
                float r = fmaxf(acc[j][c]*so[c] + bo[c], 0.f);
                if (comajor) sOut[(os*64 + cg*8+c)*120 + wl*8 + j] = r;
                else         sOut[(os*120 + wl*8+j)*64 + cg*8 + c] = r;
            }
    }
    __syncthreads();
    if (comajor) {
        for (int f = t; f < 128*30; f += 256) {
            int q  = f % 30, r = f / 30;
            int os2 = r >> 6, co = r & 63;
            int row = y0 + by*2 + os2;
            int w   = w0 + q*4;
            if (by*2 + os2 < nrows && (unsigned)row < (unsigned)GH && w < GW) {
                float4 v = *(const float4*)&sOut[(os2*64 + co)*120 + q*4];
                *(float4*)&dst[(long)co*sC + (long)od*sD + (long)(row - dst_h0)*sH + w] = v;
            }
        }
    } else {
        for (int f = t; f < 2*120*16; f += 256) {
            int ci4 = f & 15;
            int rem = f >> 4;
            int w   = rem % 120;
            int os2 = rem / 120;
            int row = y0 + by*2 + os2;
            int ww  = w0 + w;
            if (by*2 + os2 < nrows && (unsigned)row < (unsigned)GH && ww < GW) {
                float4 v = *(const float4*)&sOut[(os2*120 + w)*64 + ci4*4];
                *(float4*)&dst[(long)od*sD + (long)(row - dst_h0)*sH + (long)ww*64 + ci4*4] = v;
            }
        }
    }
}

// ---------------------------------------------------------------------------
extern "C" void kernel_launch(void* const* d_in, const int* in_sizes, int n_in,
                              void* d_out, int out_size, void* d_ws, size_t ws_size,
                              hipStream_t stream)
{
    const float* feats = (const float*)d_in[0];
    const int*   nvox  = (const int*)d_in[1];
    const int*   coors = (const int*)d_in[2];
    const float* w1  = (const float*)d_in[4];
    const float* g1  = (const float*)d_in[5];
    const float* b1  = (const float*)d_in[6];
    const float* w2  = (const float*)d_in[7];
    const float* g2  = (const float*)d_in[8];
    const float* b2  = (const float*)d_in[9];
    const float* wl  = (const float*)d_in[10];
    const float* gl  = (const float*)d_in[11];
    const float* bl  = (const float*)d_in[12];
    const float* wc1 = (const float*)d_in[13];
    const float* gc1 = (const float*)d_in[14];
    const float* bc1 = (const float*)d_in[15];
    const float* wc2 = (const float*)d_in[16];
    const float* gc2 = (const float*)d_in[17];
    const float* bc2 = (const float*)d_in[18];
    const float* wc3 = (const float*)d_in[19];
    const float* gc3 = (const float*)d_in[20];
    const float* bc3 = (const float*)d_in[21];

    int N = in_sizes[1];            // 20000 voxels

    auto al = [](size_t b) { return (b + 255) & ~(size_t)255; };

    // --- choose strip count NS: smallest NS whose workspace fits ws_size ---
    size_t winB = al((size_t)10*GH*GW*4);
    size_t voxB = al((size_t)N*128*4);
    size_t w1B  = al((size_t)27*128*64*4);
    size_t w23B = al((size_t)27*64*64*4);
    size_t wlB  = al((size_t)128*128*4);
    int NS = 16;
    const int cand[5] = {1, 2, 4, 8, 16};
    for (int k = 0; k < 5; ++k) {
        int ns = cand[k], sh = 400/ns, ar = sh + 4, xr = sh + 2;
        size_t tot = al((size_t)5*ar*GW*64*4) + al((size_t)3*xr*GW*64*4)
                   + winB + voxB + w1B + 2*w23B + wlB + al((size_t)ns*N*4) + 512;
        if (tot + (1<<16) <= ws_size) { NS = ns; break; }
    }
    int SH = 400/NS, AR = SH + 4, XR = SH + 2;

    char* ws = (char*)d_ws;
    size_t off = 0;
    auto alloc = [&](size_t bytes) -> void* {
        void* p = ws + off; off += al(bytes); return p;
    };
    size_t accB = (size_t)5*AR*GW*64*4;
    size_t actB = (size_t)3*XR*GW*64*4;
    float* accS   = (float*)alloc(accB);
    float* actS   = (float*)alloc(actB);
    int*   winner = (int*)alloc((size_t)10*GH*GW*4);
    float* voxw   = (float*)alloc((size_t)N*128*4);
    float* wt1    = (float*)alloc((size_t)27*128*64*4);
    float* wt2    = (float*)alloc((size_t)27*64*64*4);
    float* wt3    = (float*)alloc((size_t)27*64*64*4);
    float* wtl    = (float*)alloc((size_t)128*128*4);
    int*   list   = (int*)alloc((size_t)NS*N*4);
    int*   cnt    = (int*)alloc(256);

    hipMemsetAsync(winner, 0xFF, (size_t)10*GH*GW*4, stream);
    hipMemsetAsync(cnt, 0, 256, stream);

    k_tr_w<<<(27*128*64 + 255)/256, 256, 0, stream>>>(wc1, wt1, 128, 64);
    k_tr_wg<<<(27*64*64 + 255)/256, 256, 0, stream>>>(wc2, wt2);
    k_tr_wg<<<(27*64*64 + 255)/256, 256, 0, stream>>>(wc3, wt3);
    k_tr_lin<<<64, 256, 0, stream>>>(wl, wtl);

    k_winner<<<(N + 255)/256, 256, 0, stream>>>(coors, winner, N);
    k_lists<<<(N + 255)/256, 256, 0, stream>>>(coors, list, cnt, N, SH, NS);
    k_vfe<<<N, 128, 0, stream>>>(feats, nvox, w1, g1, b1, w2, g2, b2, wtl, gl, bl, voxw);

    for (int s = 0; s < NS; ++s) {
        hipMemsetAsync(accS, 0, accB, stream);
        k_scat<<<(N + 31)/32, 256, 0, stream>>>(
            (const float4*)voxw, coors, winner, (const float4*)wt1,
            accS, list + (long)s*N, cnt + s, s*SH - 2, AR);
        // conv2: out rows [s*SH-1, s*SH+SH+1); src accS raw (fuse bn1+relu),
        // dst actS channels-last (sW=64), bn2+relu on write
        k_conv<<<dim3(3, (SH+2+1)/2, 3), 256, 0, stream>>>(
            accS, s*SH - 2, (long)AR*GW*64,
            actS, s*SH - 1, 1L, (long)XR*GW*64, (long)GW*64, 64L,
            wt2, gc1, bc1, gc2, bc2,
            5, 1, 0, s*SH - 1, SH + 2);
        // conv3: out rows [s*SH, (s+1)*SH); src actS activated; dst d_out
        // co-major (sW=1), channel = co*2 + od
        k_conv<<<dim3(3, (SH+1)/2, 2), 256, 0, stream>>>(
            actS, s*SH - 1, (long)XR*GW*64,
            (float*)d_out, 0, (long)2*GH*GW, (long)GH*GW, (long)GW, 1L,
            wt3, nullptr, nullptr, gc3, bc3,
            3, 2, 1, s*SH, SH);
    }
}

// Round 5
// 3125.598 us; speedup vs baseline: 8.8241x; 1.0007x over previous
//
#include <hip/hip_runtime.h>
#include <hip/hip_bf16.h>

#define BNC 0.99950037f   // 1/sqrt(1+1e-3), BN eval scale factor
#define GH 400
#define GW 352

// LDS column dilation: insert 4 floats per 64 -> 16 lanes at 32B stride land
// 2-per-bank-quad (free) instead of 4-way conflict.
#define PHYS(c) ((c) + (((c) >> 6) << 2))

// ---------------------------------------------------------------------------
// Winner grid: last voxel index wins for duplicate cells (matches np fancy-set)
// ---------------------------------------------------------------------------
__global__ void k_winner(const int* __restrict__ coors, int* __restrict__ winner, int N) {
    int i = blockIdx.x * 256 + threadIdx.x;
    if (i >= N) return;
    int d = coors[i*4+1], h = coors[i*4+2], w = coors[i*4+3];
    atomicMax(&winner[(d*GH + h)*GW + w], i);
}

// ---------------------------------------------------------------------------
__global__ void k_lists(const int* __restrict__ coors, int* __restrict__ list,
                        int* __restrict__ cnt, int N, int SH, int NS) {
    int i = blockIdx.x * 256 + threadIdx.x;
    if (i >= N) return;
    int h = coors[i*4+2];
    for (int s = 0; s < NS; ++s) {
        int lo = s*SH - 3, hi = s*SH + SH + 3;
        if (h >= lo && h < hi) {
            int p = atomicAdd(&cnt[s], 1);
            list[(long)s*N + p] = i;
        }
    }
}

// ---------------------------------------------------------------------------
// Weight transpose for conv1/scatter: OIDHW -> [tap][ci4][co][4]
// ---------------------------------------------------------------------------
__global__ void k_tr_w(const float* __restrict__ w, float* __restrict__ wt, int CI, int CO) {
    int idx = blockIdx.x * 256 + threadIdx.x;
    int total = 27 * CI * CO;
    if (idx >= total) return;
    int j   = idx & 3;
    int t1  = idx >> 2;
    int co  = t1 % CO;
    int t2  = t1 / CO;
    int ci4 = t2 % (CI/4);
    int tap = t2 / (CI/4);
    int ci  = ci4*4 + j;
    wt[idx] = w[(co*CI + ci)*27 + tap];
}

// Weight transpose for dense convs: OIDHW -> [tap][ci][co]
__global__ void k_tr_wg(const float* __restrict__ w, float* __restrict__ wt) {
    int idx = blockIdx.x * 256 + threadIdx.x;
    if (idx >= 27*64*64) return;
    int co  = idx & 63;
    int ci  = (idx >> 6) & 63;
    int tap = idx >> 12;
    wt[idx] = w[(co*64 + ci)*27 + tap];
}

// Linear-layer weight transpose: wl[u][c] -> WT[c][u]
__global__ void k_tr_lin(const float* __restrict__ wl, float* __restrict__ WT) {
    int idx = blockIdx.x * 256 + threadIdx.x;
    if (idx >= 16384) return;
    int u = idx & 127, c = idx >> 7;
    WT[c*128 + u] = wl[u*128 + c];
}

// Input-activation table for convs: [0:64) gc1*BNC, [64:128) bc1,
// [128:192) 1.0, [192:256) 0.0 (identity block for conv3)
__global__ void k_prep(const float* __restrict__ g, const float* __restrict__ b,
                       float* __restrict__ out) {
    int i = threadIdx.x;
    if (i < 64)       out[i] = g[i] * BNC;
    else if (i < 128) out[i] = b[i-64];
    else if (i < 192) out[i] = 1.f;
    else              out[i] = 0.f;
}

// ---------------------------------------------------------------------------
// VFE: one block (128 thr) per voxel (unchanged from round 4).
// ---------------------------------------------------------------------------
__global__ __launch_bounds__(128) void k_vfe(
    const float* __restrict__ feats, const int* __restrict__ nvox,
    const float* __restrict__ w1, const float* __restrict__ g1g, const float* __restrict__ b1g,
    const float* __restrict__ w2g, const float* __restrict__ g2g, const float* __restrict__ b2g,
    const float* __restrict__ WT, const float* __restrict__ glg, const float* __restrict__ blg,
    float* __restrict__ voxelwise)
{
    __shared__ float F[35*8];
    __shared__ float W1s[16*8];
    __shared__ float SG1[16], SB1[16];
    __shared__ float X1[35*36];
    __shared__ float X2[35*132];
    __shared__ float RED[8*128];
    __shared__ float AGG1[16];
    __shared__ float AGG2[64];
    __shared__ float MEANS[3];

    int tid = threadIdx.x;
    int vox = blockIdx.x;
    int nv  = nvox[vox];

    const float* fsrc = feats + (long)vox * 140;
    for (int idx = tid; idx < 140; idx += 128) { int t = idx>>2, c = idx&3; F[t*8+c] = fsrc[idx]; }
    if (tid < 35) F[tid*8+7] = 0.f;
    if (tid < 112) { int u = tid/7, c = tid - u*7; W1s[u*8+c] = w1[tid]; }
    if (tid < 16)  { W1s[tid*8+7] = 0.f; SG1[tid] = g1g[tid]*BNC; SB1[tid] = b1g[tid]; }
    __syncthreads();

    if (tid < 3) {
        float s = 0.f;
        for (int t = 0; t < 35; ++t) s += F[t*8 + tid];
        MEANS[tid] = s / (float)nv;
    }
    __syncthreads();
    for (int idx = tid; idx < 105; idx += 128) { int t = idx/3, c = idx - t*3; F[t*8+4+c] = F[t*8+c] - MEANS[c]; }
    __syncthreads();

    {
        const float4* Ff4  = (const float4*)F;
        const float4* W1f4 = (const float4*)W1s;
        for (int idx = tid; idx < 560; idx += 128) {
            int t = idx >> 4, u = idx & 15;
            float4 a0 = Ff4[t*2], a1 = Ff4[t*2+1];
            float4 b0 = W1f4[u*2], b1v = W1f4[u*2+1];
            float a = a0.x*b0.x + a0.y*b0.y + a0.z*b0.z + a0.w*b0.w
                    + a1.x*b1v.x + a1.y*b1v.y + a1.z*b1v.z + a1.w*b1v.w;
            X1[t*36+u] = fmaxf(a*SG1[u] + SB1[u], 0.f);
        }
    }
    __syncthreads();
    if (tid < 16) {
        float m = 0.f;
        for (int t = 0; t < 35; ++t) m = fmaxf(m, X1[t*36+tid]);
        AGG1[tid] = m;
    }
    __syncthreads();
    {
        float4* X1f4 = (float4*)X1;
        const float4* A1f4 = (const float4*)AGG1;
        for (int idx = tid; idx < nv*4; idx += 128) {
            int t = idx >> 2, k = idx & 3;
            X1f4[t*9 + 4 + k] = A1f4[k];
        }
    }
    __syncthreads();

    {
        int u = tid & 63, tg = tid >> 6;
        float w2r[32];
        const float4* wsrc = (const float4*)(w2g + u*32);
        #pragma unroll
        for (int q = 0; q < 8; ++q) {
            float4 w4 = wsrc[q];
            w2r[q*4] = w4.x; w2r[q*4+1] = w4.y; w2r[q*4+2] = w4.z; w2r[q*4+3] = w4.w;
        }
        float su = g2g[u]*BNC, bu = b2g[u];
        float lm = (nv < 35) ? fmaxf(bu, 0.f) : 0.f;
        for (int t = tg; t < nv; t += 2) {
            const float4* xr = (const float4*)(X1 + t*36);
            float a = 0.f;
            #pragma unroll
            for (int q = 0; q < 8; ++q) {
                float4 x4 = xr[q];
                a += x4.x*w2r[q*4] + x4.y*w2r[q*4+1] + x4.z*w2r[q*4+2] + x4.w*w2r[q*4+3];
            }
            float h = fmaxf(a*su + bu, 0.f);
            X2[t*132 + u] = h;
            lm = fmaxf(lm, h);
        }
        RED[tg*64 + u] = lm;
    }
    __syncthreads();
    if (tid < 64) AGG2[tid] = fmaxf(RED[tid], RED[64+tid]);
    __syncthreads();
    {
        float4* X2f4 = (float4*)X2;
        const float4* A2f4 = (const float4*)AGG2;
        for (int idx = tid; idx < nv*16; idx += 128) {
            int t = idx >> 4, k = idx & 15;
            X2f4[t*33 + 16 + k] = A2f4[k];
        }
    }
    __syncthreads();

    {
        int ug = tid & 15, tg4 = tid >> 4;
        int u0 = ug * 8;
        int kmax = (nv > tg4) ? ((nv - tg4 + 7) >> 3) : 0;
        float acc[5][8];
        #pragma unroll
        for (int k = 0; k < 5; ++k)
            #pragma unroll
            for (int j = 0; j < 8; ++j) acc[k][j] = 0.f;

        const float4* X2f4 = (const float4*)X2;
        const float4* WTf4 = (const float4*)WT;
        for (int c4 = 0; c4 < 32; ++c4) {
            float4 wv[8];
            #pragma unroll
            for (int cc = 0; cc < 4; ++cc) {
                wv[cc*2]   = WTf4[(c4*4+cc)*32 + ug*2];
                wv[cc*2+1] = WTf4[(c4*4+cc)*32 + ug*2 + 1];
            }
            #pragma unroll
            for (int k = 0; k < 5; ++k) {
                if (k < kmax) {
                    int t = tg4 + (k << 3);
                    float4 x4 = X2f4[t*33 + c4];
                    #pragma unroll
                    for (int cc = 0; cc < 4; ++cc) {
                        float xs = (cc == 0) ? x4.x : (cc == 1) ? x4.y : (cc == 2) ? x4.z : x4.w;
                        acc[k][0] = fmaf(xs, wv[cc*2].x,   acc[k][0]);
                        acc[k][1] = fmaf(xs, wv[cc*2].y,   acc[k][1]);
                        acc[k][2] = fmaf(xs, wv[cc*2].z,   acc[k][2]);
                        acc[k][3] = fmaf(xs, wv[cc*2].w,   acc[k][3]);
                        acc[k][4] = fmaf(xs, wv[cc*2+1].x, acc[k][4]);
                        acc[k][5] = fmaf(xs, wv[cc*2+1].y, acc[k][5]);
                        acc[k][6] = fmaf(xs, wv[cc*2+1].z, acc[k][6]);
                        acc[k][7] = fmaf(xs, wv[cc*2+1].w, acc[k][7]);
                    }
                }
            }
        }
        float4 g0 = *(const float4*)(glg + u0), g1v = *(const float4*)(glg + u0 + 4);
        float4 b0 = *(const float4*)(blg + u0), b1v = *(const float4*)(blg + u0 + 4);
        float sg[8] = {g0.x*BNC, g0.y*BNC, g0.z*BNC, g0.w*BNC,
                       g1v.x*BNC, g1v.y*BNC, g1v.z*BNC, g1v.w*BNC};
        float sb[8] = {b0.x, b0.y, b0.z, b0.w, b1v.x, b1v.y, b1v.z, b1v.w};
        float m[8];
        #pragma unroll
        for (int j = 0; j < 8; ++j) m[j] = 0.f;
        #pragma unroll
        for (int k = 0; k < 5; ++k) {
            if (k < kmax) {
                #pragma unroll
                for (int j = 0; j < 8; ++j)
                    m[j] = fmaxf(m[j], fmaxf(acc[k][j]*sg[j] + sb[j], 0.f));
            }
        }
        #pragma unroll
        for (int j = 0; j < 8; ++j) RED[tg4*128 + u0 + j] = m[j];
    }
    __syncthreads();
    {
        float m = RED[tid];
        #pragma unroll
        for (int r = 1; r < 8; ++r) m = fmaxf(m, RED[r*128 + tid]);
        voxelwise[(long)vox*128 + tid] = m;
    }
}

// ---------------------------------------------------------------------------
// conv1 as sparse scatter (round-4 version + all-invalid tap skip).
// ---------------------------------------------------------------------------
__global__ __launch_bounds__(256) void k_scat(
    const float4* __restrict__ voxf4, const int* __restrict__ coors,
    const int* __restrict__ winner, const float4* __restrict__ Wt1,
    float* __restrict__ accS, const int* __restrict__ list,
    const int* __restrict__ cnt, int h_lo, int AR)
{
    __shared__ float4 sF[32][32];
    __shared__ int sI[32], sD[32], sH_[32], sWc[32], sV[32];
    int tid = threadIdx.x;
    int cn = cnt[0];
    int v0 = blockIdx.x * 32;
    if (v0 >= cn) return;

    if (tid < 32) {
        int slot = v0 + tid;
        int i = -1, d = 0, h = 0, w = 0, ok = 0;
        if (slot < cn) {
            i = list[slot];
            d = coors[i*4+1]; h = coors[i*4+2]; w = coors[i*4+3];
            ok = (winner[(d*GH + h)*GW + w] == i);
        }
        sI[tid] = i; sD[tid] = d; sH_[tid] = h; sWc[tid] = w; sV[tid] = ok;
    }
    __syncthreads();
    for (int idx = tid; idx < 1024; idx += 256) {
        int v = idx >> 5, c = idx & 31;
        int vi = sI[v];
        if (vi >= 0) sF[v][c] = voxf4[(long)vi*32 + c];
    }
    __syncthreads();

    int co = tid & 63, wv = tid >> 6;
    for (int tap = 0; tap < 27; ++tap) {
        int kd = tap/9, kh = (tap/3)%3, kw = tap%3;
        bool okv[8]; long cell[8];
        bool anyv = false;
        #pragma unroll
        for (int s8 = 0; s8 < 8; ++s8) {
            int v = wv*8 + s8;
            int od2 = sD[v] + 1 - kd;
            int oh  = sH_[v] + 1 - kh;
            int ow  = sWc[v] + 1 - kw;
            okv[s8] = sV[v] && !(od2 & 1) && (unsigned)od2 < 10u
                      && oh >= 0 && oh < GH && oh >= h_lo && oh < h_lo + AR
                      && (unsigned)ow < (unsigned)GW;
            anyv |= okv[s8];
            cell[s8] = okv[s8] ? ((long)((od2>>1)*AR + (oh - h_lo))*GW + ow) : 0;
        }
        if (!anyv) continue;   // wave-uniform
        float acc[8];
        #pragma unroll
        for (int s8 = 0; s8 < 8; ++s8) acc[s8] = 0.f;
        const float4* wbase = Wt1 + (long)tap*2048 + co;
        for (int c4 = 0; c4 < 32; ++c4) {
            float4 wq = wbase[c4*64];
            #pragma unroll
            for (int s8 = 0; s8 < 8; ++s8) {
                if (okv[s8]) {
                    float4 f4 = sF[wv*8 + s8][c4];
                    acc[s8] += f4.x*wq.x + f4.y*wq.y + f4.z*wq.z + f4.w*wq.w;
                }
            }
        }
        #pragma unroll
        for (int s8 = 0; s8 < 8; ++s8) {
            if (okv[s8]) atomicAdd(&accS[cell[s8]*64 + co], acc[s8]);
        }
    }
}

// ---------------------------------------------------------------------------
// Dense conv3d, implicit-GEMM register tiling, dilated-column LDS layout.
// sIn logical [os][ci][w-window]; physical col = PHYS(c), row stride 128
// floats. Input BN scale/bias from precomputed global table gact.
// ---------------------------------------------------------------------------
__global__ __launch_bounds__(256) void k_conv(
    const float* __restrict__ src, int src_h0, long src_dpitch,
    float* __restrict__ dst, int dst_h0, long sC, long sD, long sH, long sW,
    const float* __restrict__ wt,
    const float* __restrict__ gact,    // [0:64) scale, [64:128) bias
    const float* __restrict__ gout, const float* __restrict__ bout,
    int D_in, int d_stride, int d_pad, int y0, int nrows)
{
    __shared__ __align__(16) float sInF[16384];   // 64 KB, reused as sOut

    int t  = threadIdx.x;
    int wl = t & 15;            // wl==15 idle in compute (tile = 15*8 = 120 w)
    int cg = (t >> 4) & 7;
    int os = t >> 7;
    int w0 = blockIdx.x * 120;
    int by = blockIdx.y;
    int od = blockIdx.z;

    int wle  = (wl < 15) ? wl : 0;                      // clamp idle lane
    int woff = wle*8 + ((wle >> 3) << 2);               // PHYS(wle*8)
    int d2   = ((wle & 7) == 7) ? 12 : 8;               // A2 offset (group hop)

    float acc[8][8];
    #pragma unroll
    for (int j = 0; j < 8; ++j)
        #pragma unroll
        for (int c = 0; c < 8; ++c) acc[j][c] = 0.f;

    for (int kd = 0; kd < 3; ++kd) {
        int dp = od*d_stride + kd - d_pad;
        if (dp < 0 || dp >= D_in) continue;            // uniform
        for (int kh = 0; kh < 3; ++kh) {
            __syncthreads();                           // protect prior LDS reads
            {
                const float* sbase = src + dp*src_dpitch;
                for (int f = t; f < 4096; f += 256) {  // 2 os x 16 ci4 x 128 wloc
                    int wloc = f & 127;
                    if (wloc < 122) {
                        int ci4 = (f >> 7) & 15;
                        int os2 = f >> 11;
                        int hp = y0 + by*2 + os2 + kh - 1;
                        int w  = w0 - 1 + wloc;
                        float4 v = make_float4(0.f, 0.f, 0.f, 0.f);
                        if ((unsigned)hp < (unsigned)GH && (unsigned)w < (unsigned)GW) {
                            v = *(const float4*)(sbase + ((long)(hp - src_h0)*GW + w)*64 + ci4*4);
                            float4 gs = *(const float4*)(gact + ci4*4);
                            float4 bs = *(const float4*)(gact + 64 + ci4*4);
                            v.x = fmaxf(v.x*gs.x + bs.x, 0.f);
                            v.y = fmaxf(v.y*gs.y + bs.y, 0.f);
                            v.z = fmaxf(v.z*gs.z + bs.z, 0.f);
                            v.w = fmaxf(v.w*gs.w + bs.w, 0.f);
                        }
                        float* col = &sInF[(os2*64 + ci4*4)*128 + PHYS(wloc)];
                        col[0]   = v.x;
                        col[128] = v.y;
                        col[256] = v.z;
                        col[384] = v.w;
                    }
                }
            }
            __syncthreads();
            const float* wbase = wt + ((kd*3 + kh)*3) * 4096 + cg*8;
            const float* ipb = &sInF[(os*64)*128] + woff;
            #pragma unroll 2
            for (int ci = 0; ci < 64; ++ci) {
                const float* ip = ipb + ci*128;
                float4 A0 = *(const float4*)(ip);
                float4 A1 = *(const float4*)(ip + 4);
                float4 A2 = *(const float4*)(ip + d2);
                float win[12] = {A0.x,A0.y,A0.z,A0.w, A1.x,A1.y,A1.z,A1.w,
                                 A2.x,A2.y,A2.z,A2.w};
                #pragma unroll
                for (int kw = 0; kw < 3; ++kw) {
                    const float4* wp = (const float4*)(wbase + (kw<<12) + (ci<<6));
                    float4 B0 = wp[0], B1 = wp[1];
                    #pragma unroll
                    for (int j = 0; j < 8; ++j) {
                        float av = win[j + kw];
                        acc[j][0] = fmaf(av, B0.x, acc[j][0]);
                        acc[j][1] = fmaf(av, B0.y, acc[j][1]);
                        acc[j][2] = fmaf(av, B0.z, acc[j][2]);
                        acc[j][3] = fmaf(av, B0.w, acc[j][3]);
                        acc[j][4] = fmaf(av, B1.x, acc[j][4]);
                        acc[j][5] = fmaf(av, B1.y, acc[j][5]);
                        acc[j][6] = fmaf(av, B1.z, acc[j][6]);
                        acc[j][7] = fmaf(av, B1.w, acc[j][7]);
                    }
                }
            }
        }
    }

    // ---- epilogue: bn+relu, LDS transpose, coalesced store ----
    float so[8], bo[8];
    #pragma unroll
    for (int c = 0; c < 8; ++c) { so[c] = gout[cg*8+c]*BNC; bo[c] = bout[cg*8+c]; }
    __syncthreads();
    float* sOut = sInF;
    bool comajor = (sW == 1);
    if (wl < 15) {
        #pragma unroll
        for (int j = 0; j < 8; ++j)
            #pragma unroll
            for (int c = 0; c < 8; ++c) {
                float r = fmaxf(acc[j][c]*so[c] + bo[c], 0.f);
                if (comajor) sOut[(os*64 + cg*8+c)*120 + wl*8 + j] = r;
                else         sOut[(os*120 + wl*8+j)*64 + cg*8 + c] = r;
            }
    }
    __syncthreads();
    if (comajor) {
        for (int f = t; f < 128*30; f += 256) {
            int q  = f % 30, r = f / 30;
            int os2 = r >> 6, co = r & 63;
            int row = y0 + by*2 + os2;
            int w   = w0 + q*4;
            if (by*2 + os2 < nrows && (unsigned)row < (unsigned)GH && w < GW) {
                float4 v = *(const float4*)&sOut[(os2*64 + co)*120 + q*4];
                *(float4*)&dst[(long)co*sC + (long)od*sD + (long)(row - dst_h0)*sH + w] = v;
            }
        }
    } else {
        for (int f = t; f < 2*120*16; f += 256) {
            int ci4 = f & 15;
            int rem = f >> 4;
            int w   = rem % 120;
            int os2 = rem / 120;
            int row = y0 + by*2 + os2;
            int ww  = w0 + w;
            if (by*2 + os2 < nrows && (unsigned)row < (unsigned)GH && ww < GW) {
                float4 v = *(const float4*)&sOut[(os2*120 + w)*64 + ci4*4];
                *(float4*)&dst[(long)od*sD + (long)(row - dst_h0)*sH + (long)ww*64 + ci4*4] = v;
            }
        }
    }
}

// ---------------------------------------------------------------------------
extern "C" void kernel_launch(void* const* d_in, const int* in_sizes, int n_in,
                              void* d_out, int out_size, void* d_ws, size_t ws_size,
                              hipStream_t stream)
{
    const float* feats = (const float*)d_in[0];
    const int*   nvox  = (const int*)d_in[1];
    const int*   coors = (const int*)d_in[2];
    const float* w1  = (const float*)d_in[4];
    const float* g1  = (const float*)d_in[5];
    const float* b1  = (const float*)d_in[6];
    const float* w2  = (const float*)d_in[7];
    const float* g2  = (const float*)d_in[8];
    const float* b2  = (const float*)d_in[9];
    const float* wl  = (const float*)d_in[10];
    const float* gl  = (const float*)d_in[11];
    const float* bl  = (const float*)d_in[12];
    const float* wc1 = (const float*)d_in[13];
    const float* gc1 = (const float*)d_in[14];
    const float* bc1 = (const float*)d_in[15];
    const float* wc2 = (const float*)d_in[16];
    const float* gc2 = (const float*)d_in[17];
    const float* bc2 = (const float*)d_in[18];
    const float* wc3 = (const float*)d_in[19];
    const float* gc3 = (const float*)d_in[20];
    const float* bc3 = (const float*)d_in[21];

    int N = in_sizes[1];            // 20000 voxels

    auto al = [](size_t b) { return (b + 255) & ~(size_t)255; };

    size_t winB = al((size_t)10*GH*GW*4);
    size_t voxB = al((size_t)N*128*4);
    size_t w1B  = al((size_t)27*128*64*4);
    size_t w23B = al((size_t)27*64*64*4);
    size_t wlB  = al((size_t)128*128*4);
    int NS = 16;
    const int cand[5] = {1, 2, 4, 8, 16};
    for (int k = 0; k < 5; ++k) {
        int ns = cand[k], sh = 400/ns, ar = sh + 4, xr = sh + 2;
        size_t tot = al((size_t)5*ar*GW*64*4) + al((size_t)3*xr*GW*64*4)
                   + winB + voxB + w1B + 2*w23B + wlB + al((size_t)ns*N*4) + 2048;
        if (tot + (1<<16) <= ws_size) { NS = ns; break; }
    }
    int SH = 400/NS, AR = SH + 4, XR = SH + 2;

    char* ws = (char*)d_ws;
    size_t off = 0;
    auto alloc = [&](size_t bytes) -> void* {
        void* p = ws + off; off += al(bytes); return p;
    };
    size_t accB = (size_t)5*AR*GW*64*4;
    size_t actB = (size_t)3*XR*GW*64*4;
    float* accS   = (float*)alloc(accB);
    float* actS   = (float*)alloc(actB);
    int*   winner = (int*)alloc((size_t)10*GH*GW*4);
    float* voxw   = (float*)alloc((size_t)N*128*4);
    float* wt1    = (float*)alloc((size_t)27*128*64*4);
    float* wt2    = (float*)alloc((size_t)27*64*64*4);
    float* wt3    = (float*)alloc((size_t)27*64*64*4);
    float* wtl    = (float*)alloc((size_t)128*128*4);
    float* gact   = (float*)alloc(256*4);
    int*   list   = (int*)alloc((size_t)NS*N*4);
    int*   cnt    = (int*)alloc(256);

    hipMemsetAsync(winner, 0xFF, (size_t)10*GH*GW*4, stream);
    hipMemsetAsync(cnt, 0, 256, stream);

    k_tr_w<<<(27*128*64 + 255)/256, 256, 0, stream>>>(wc1, wt1, 128, 64);
    k_tr_wg<<<(27*64*64 + 255)/256, 256, 0, stream>>>(wc2, wt2);
    k_tr_wg<<<(27*64*64 + 255)/256, 256, 0, stream>>>(wc3, wt3);
    k_tr_lin<<<64, 256, 0, stream>>>(wl, wtl);
    k_prep<<<1, 256, 0, stream>>>(gc1, bc1, gact);

    k_winner<<<(N + 255)/256, 256, 0, stream>>>(coors, winner, N);
    k_lists<<<(N + 255)/256, 256, 0, stream>>>(coors, list, cnt, N, SH, NS);
    k_vfe<<<N, 128, 0, stream>>>(feats, nvox, w1, g1, b1, w2, g2, b2, wtl, gl, bl, voxw);

    for (int s = 0; s < NS; ++s) {
        hipMemsetAsync(accS, 0, accB, stream);
        k_scat<<<(N + 31)/32, 256, 0, stream>>>(
            (const float4*)voxw, coors, winner, (const float4*)wt1,
            accS, list + (long)s*N, cnt + s, s*SH - 2, AR);
        // conv2: src accS raw (fuse bn1+relu via gact), dst actS channels-last
        k_conv<<<dim3(3, (SH+2+1)/2, 3), 256, 0, stream>>>(
            accS, s*SH - 2, (long)AR*GW*64,
            actS, s*SH - 1, 1L, (long)XR*GW*64, (long)GW*64, 64L,
            wt2, gact, gc2, bc2,
            5, 1, 0, s*SH - 1, SH + 2);
        // conv3: src actS activated (identity via gact+128); dst d_out co-major
        k_conv<<<dim3(3, (SH+1)/2, 2), 256, 0, stream>>>(
            actS, s*SH - 1, (long)XR*GW*64,
            (float*)d_out, 0, (long)2*GH*GW, (long)GH*GW, (long)GW, 1L,
            wt3, gact + 128, gc3, bc3,
            3, 2, 1, s*SH, SH);
    }
}

// Round 6
// 1634.482 us; speedup vs baseline: 16.8742x; 1.9123x over previous
//
#include <hip/hip_runtime.h>
#include <hip/hip_bf16.h>

#define BNC 0.99950037f   // 1/sqrt(1+1e-3), BN eval scale factor
#define GH 400
#define GW 352

typedef __bf16 bf16_t;
typedef __bf16 bf16x8 __attribute__((ext_vector_type(8)));
typedef float f32x4 __attribute__((ext_vector_type(4)));

// ---------------------------------------------------------------------------
// Winner grid: last voxel index wins for duplicate cells (matches np fancy-set)
// ---------------------------------------------------------------------------
__global__ void k_winner(const int* __restrict__ coors, int* __restrict__ winner, int N) {
    int i = blockIdx.x * 256 + threadIdx.x;
    if (i >= N) return;
    int d = coors[i*4+1], h = coors[i*4+2], w = coors[i*4+3];
    atomicMax(&winner[(d*GH + h)*GW + w], i);
}

// ---------------------------------------------------------------------------
__global__ void k_lists(const int* __restrict__ coors, int* __restrict__ list,
                        int* __restrict__ cnt, int N, int SH, int NS) {
    int i = blockIdx.x * 256 + threadIdx.x;
    if (i >= N) return;
    int h = coors[i*4+2];
    for (int s = 0; s < NS; ++s) {
        int lo = s*SH - 3, hi = s*SH + SH + 3;
        if (h >= lo && h < hi) {
            int p = atomicAdd(&cnt[s], 1);
            list[(long)s*N + p] = i;
        }
    }
}

// ---------------------------------------------------------------------------
// Weight transpose for conv1/scatter: OIDHW -> [tap][ci4][co][4]
// ---------------------------------------------------------------------------
__global__ void k_tr_w(const float* __restrict__ w, float* __restrict__ wt, int CI, int CO) {
    int idx = blockIdx.x * 256 + threadIdx.x;
    int total = 27 * CI * CO;
    if (idx >= total) return;
    int j   = idx & 3;
    int t1  = idx >> 2;
    int co  = t1 % CO;
    int t2  = t1 / CO;
    int ci4 = t2 % (CI/4);
    int tap = t2 / (CI/4);
    int ci  = ci4*4 + j;
    wt[idx] = w[(co*CI + ci)*27 + tap];
}

// Linear-layer weight transpose: wl[u][c] -> WT[c][u]
__global__ void k_tr_lin(const float* __restrict__ wl, float* __restrict__ WT) {
    int idx = blockIdx.x * 256 + threadIdx.x;
    if (idx >= 16384) return;
    int u = idx & 127, c = idx >> 7;
    WT[c*128 + u] = wl[u*128 + c];
}

// Input-activation table for convs: [0:64) gc1*BNC, [64:128) bc1,
// [128:192) 1.0, [192:256) 0.0 (identity block for conv3)
__global__ void k_prep(const float* __restrict__ g, const float* __restrict__ b,
                       float* __restrict__ out) {
    int i = threadIdx.x;
    if (i < 64)       out[i] = g[i] * BNC;
    else if (i < 128) out[i] = b[i-64];
    else if (i < 192) out[i] = 1.f;
    else              out[i] = 0.f;
}

// ---------------------------------------------------------------------------
// Pack 64x64x27 conv weights (OIDHW fp32) into MFMA B-fragment order, split
// into hi/lo bf16. Frag index fb = (s*4 + ct)*64 + lane, s = tap*2 + h.
// Lane l of B[k][n]: n(co) = ct*16 + (l&15), k(ci) = h*32 + (l>>4)*8 + j.
// ---------------------------------------------------------------------------
__global__ void k_packw(const float* __restrict__ w, bf16_t* __restrict__ wh,
                        bf16_t* __restrict__ wlo) {
    int i = blockIdx.x * 256 + threadIdx.x;    // over 54*4*64 = 13824 frag-lanes
    if (i >= 13824) return;
    int lane = i & 63, ct = (i >> 6) & 3, s = i >> 8;
    int tap = s >> 1, h = s & 1;
    int kg = lane >> 4, wl = lane & 15;
    int co = ct*16 + wl;
    #pragma unroll
    for (int j = 0; j < 8; ++j) {
        int ci = h*32 + kg*8 + j;
        float v = w[(co*64 + ci)*27 + tap];
        bf16_t hi = (bf16_t)v;
        wh[(long)i*8 + j]  = hi;
        wlo[(long)i*8 + j] = (bf16_t)(v - (float)hi);
    }
}

// ---------------------------------------------------------------------------
// VFE: one block (128 thr) per voxel (unchanged from round 5).
// ---------------------------------------------------------------------------
__global__ __launch_bounds__(128) void k_vfe(
    const float* __restrict__ feats, const int* __restrict__ nvox,
    const float* __restrict__ w1, const float* __restrict__ g1g, const float* __restrict__ b1g,
    const float* __restrict__ w2g, const float* __restrict__ g2g, const float* __restrict__ b2g,
    const float* __restrict__ WT, const float* __restrict__ glg, const float* __restrict__ blg,
    float* __restrict__ voxelwise)
{
    __shared__ float F[35*8];
    __shared__ float W1s[16*8];
    __shared__ float SG1[16], SB1[16];
    __shared__ float X1[35*36];
    __shared__ float X2[35*132];
    __shared__ float RED[8*128];
    __shared__ float AGG1[16];
    __shared__ float AGG2[64];
    __shared__ float MEANS[3];

    int tid = threadIdx.x;
    int vox = blockIdx.x;
    int nv  = nvox[vox];

    const float* fsrc = feats + (long)vox * 140;
    for (int idx = tid; idx < 140; idx += 128) { int t = idx>>2, c = idx&3; F[t*8+c] = fsrc[idx]; }
    if (tid < 35) F[tid*8+7] = 0.f;
    if (tid < 112) { int u = tid/7, c = tid - u*7; W1s[u*8+c] = w1[tid]; }
    if (tid < 16)  { W1s[tid*8+7] = 0.f; SG1[tid] = g1g[tid]*BNC; SB1[tid] = b1g[tid]; }
    __syncthreads();

    if (tid < 3) {
        float s = 0.f;
        for (int t = 0; t < 35; ++t) s += F[t*8 + tid];
        MEANS[tid] = s / (float)nv;
    }
    __syncthreads();
    for (int idx = tid; idx < 105; idx += 128) { int t = idx/3, c = idx - t*3; F[t*8+4+c] = F[t*8+c] - MEANS[c]; }
    __syncthreads();

    {
        const float4* Ff4  = (const float4*)F;
        const float4* W1f4 = (const float4*)W1s;
        for (int idx = tid; idx < 560; idx += 128) {
            int t = idx >> 4, u = idx & 15;
            float4 a0 = Ff4[t*2], a1 = Ff4[t*2+1];
            float4 b0 = W1f4[u*2], b1v = W1f4[u*2+1];
            float a = a0.x*b0.x + a0.y*b0.y + a0.z*b0.z + a0.w*b0.w
                    + a1.x*b1v.x + a1.y*b1v.y + a1.z*b1v.z + a1.w*b1v.w;
            X1[t*36+u] = fmaxf(a*SG1[u] + SB1[u], 0.f);
        }
    }
    __syncthreads();
    if (tid < 16) {
        float m = 0.f;
        for (int t = 0; t < 35; ++t) m = fmaxf(m, X1[t*36+tid]);
        AGG1[tid] = m;
    }
    __syncthreads();
    {
        float4* X1f4 = (float4*)X1;
        const float4* A1f4 = (const float4*)AGG1;
        for (int idx = tid; idx < nv*4; idx += 128) {
            int t = idx >> 2, k = idx & 3;
            X1f4[t*9 + 4 + k] = A1f4[k];
        }
    }
    __syncthreads();

    {
        int u = tid & 63, tg = tid >> 6;
        float w2r[32];
        const float4* wsrc = (const float4*)(w2g + u*32);
        #pragma unroll
        for (int q = 0; q < 8; ++q) {
            float4 w4 = wsrc[q];
            w2r[q*4] = w4.x; w2r[q*4+1] = w4.y; w2r[q*4+2] = w4.z; w2r[q*4+3] = w4.w;
        }
        float su = g2g[u]*BNC, bu = b2g[u];
        float lm = (nv < 35) ? fmaxf(bu, 0.f) : 0.f;
        for (int t = tg; t < nv; t += 2) {
            const float4* xr = (const float4*)(X1 + t*36);
            float a = 0.f;
            #pragma unroll
            for (int q = 0; q < 8; ++q) {
                float4 x4 = xr[q];
                a += x4.x*w2r[q*4] + x4.y*w2r[q*4+1] + x4.z*w2r[q*4+2] + x4.w*w2r[q*4+3];
            }
            float h = fmaxf(a*su + bu, 0.f);
            X2[t*132 + u] = h;
            lm = fmaxf(lm, h);
        }
        RED[tg*64 + u] = lm;
    }
    __syncthreads();
    if (tid < 64) AGG2[tid] = fmaxf(RED[tid], RED[64+tid]);
    __syncthreads();
    {
        float4* X2f4 = (float4*)X2;
        const float4* A2f4 = (const float4*)AGG2;
        for (int idx = tid; idx < nv*16; idx += 128) {
            int t = idx >> 4, k = idx & 15;
            X2f4[t*33 + 16 + k] = A2f4[k];
        }
    }
    __syncthreads();

    {
        int ug = tid & 15, tg4 = tid >> 4;
        int u0 = ug * 8;
        int kmax = (nv > tg4) ? ((nv - tg4 + 7) >> 3) : 0;
        float acc[5][8];
        #pragma unroll
        for (int k = 0; k < 5; ++k)
            #pragma unroll
            for (int j = 0; j < 8; ++j) acc[k][j] = 0.f;

        const float4* X2f4 = (const float4*)X2;
        const float4* WTf4 = (const float4*)WT;
        for (int c4 = 0; c4 < 32; ++c4) {
            float4 wv[8];
            #pragma unroll
            for (int cc = 0; cc < 4; ++cc) {
                wv[cc*2]   = WTf4[(c4*4+cc)*32 + ug*2];
                wv[cc*2+1] = WTf4[(c4*4+cc)*32 + ug*2 + 1];
            }
            #pragma unroll
            for (int k = 0; k < 5; ++k) {
                if (k < kmax) {
                    int t = tg4 + (k << 3);
                    float4 x4 = X2f4[t*33 + c4];
                    #pragma unroll
                    for (int cc = 0; cc < 4; ++cc) {
                        float xs = (cc == 0) ? x4.x : (cc == 1) ? x4.y : (cc == 2) ? x4.z : x4.w;
                        acc[k][0] = fmaf(xs, wv[cc*2].x,   acc[k][0]);
                        acc[k][1] = fmaf(xs, wv[cc*2].y,   acc[k][1]);
                        acc[k][2] = fmaf(xs, wv[cc*2].z,   acc[k][2]);
                        acc[k][3] = fmaf(xs, wv[cc*2].w,   acc[k][3]);
                        acc[k][4] = fmaf(xs, wv[cc*2+1].x, acc[k][4]);
                        acc[k][5] = fmaf(xs, wv[cc*2+1].y, acc[k][5]);
                        acc[k][6] = fmaf(xs, wv[cc*2+1].z, acc[k][6]);
                        acc[k][7] = fmaf(xs, wv[cc*2+1].w, acc[k][7]);
                    }
                }
            }
        }
        float4 g0 = *(const float4*)(glg + u0), g1v = *(const float4*)(glg + u0 + 4);
        float4 b0 = *(const float4*)(blg + u0), b1v = *(const float4*)(blg + u0 + 4);
        float sg[8] = {g0.x*BNC, g0.y*BNC, g0.z*BNC, g0.w*BNC,
                       g1v.x*BNC, g1v.y*BNC, g1v.z*BNC, g1v.w*BNC};
        float sb[8] = {b0.x, b0.y, b0.z, b0.w, b1v.x, b1v.y, b1v.z, b1v.w};
        float m[8];
        #pragma unroll
        for (int j = 0; j < 8; ++j) m[j] = 0.f;
        #pragma unroll
        for (int k = 0; k < 5; ++k) {
            if (k < kmax) {
                #pragma unroll
                for (int j = 0; j < 8; ++j)
                    m[j] = fmaxf(m[j], fmaxf(acc[k][j]*sg[j] + sb[j], 0.f));
            }
        }
        #pragma unroll
        for (int j = 0; j < 8; ++j) RED[tg4*128 + u0 + j] = m[j];
    }
    __syncthreads();
    {
        float m = RED[tid];
        #pragma unroll
        for (int r = 1; r < 8; ++r) m = fmaxf(m, RED[r*128 + tid]);
        voxelwise[(long)vox*128 + tid] = m;
    }
}

// ---------------------------------------------------------------------------
// conv1 as sparse scatter (unchanged from round 5).
// ---------------------------------------------------------------------------
__global__ __launch_bounds__(256) void k_scat(
    const float4* __restrict__ voxf4, const int* __restrict__ coors,
    const int* __restrict__ winner, const float4* __restrict__ Wt1,
    float* __restrict__ accS, const int* __restrict__ list,
    const int* __restrict__ cnt, int h_lo, int AR)
{
    __shared__ float4 sF[32][32];
    __shared__ int sI[32], sD[32], sH_[32], sWc[32], sV[32];
    int tid = threadIdx.x;
    int cn = cnt[0];
    int v0 = blockIdx.x * 32;
    if (v0 >= cn) return;

    if (tid < 32) {
        int slot = v0 + tid;
        int i = -1, d = 0, h = 0, w = 0, ok = 0;
        if (slot < cn) {
            i = list[slot];
            d = coors[i*4+1]; h = coors[i*4+2]; w = coors[i*4+3];
            ok = (winner[(d*GH + h)*GW + w] == i);
        }
        sI[tid] = i; sD[tid] = d; sH_[tid] = h; sWc[tid] = w; sV[tid] = ok;
    }
    __syncthreads();
    for (int idx = tid; idx < 1024; idx += 256) {
        int v = idx >> 5, c = idx & 31;
        int vi = sI[v];
        if (vi >= 0) sF[v][c] = voxf4[(long)vi*32 + c];
    }
    __syncthreads();

    int co = tid & 63, wv = tid >> 6;
    for (int tap = 0; tap < 27; ++tap) {
        int kd = tap/9, kh = (tap/3)%3, kw = tap%3;
        bool okv[8]; long cell[8];
        bool anyv = false;
        #pragma unroll
        for (int s8 = 0; s8 < 8; ++s8) {
            int v = wv*8 + s8;
            int od2 = sD[v] + 1 - kd;
            int oh  = sH_[v] + 1 - kh;
            int ow  = sWc[v] + 1 - kw;
            okv[s8] = sV[v] && !(od2 & 1) && (unsigned)od2 < 10u
                      && oh >= 0 && oh < GH && oh >= h_lo && oh < h_lo + AR
                      && (unsigned)ow < (unsigned)GW;
            anyv |= okv[s8];
            cell[s8] = okv[s8] ? ((long)((od2>>1)*AR + (oh - h_lo))*GW + ow) : 0;
        }
        if (!anyv) continue;   // wave-uniform
        float acc[8];
        #pragma unroll
        for (int s8 = 0; s8 < 8; ++s8) acc[s8] = 0.f;
        const float4* wbase = Wt1 + (long)tap*2048 + co;
        for (int c4 = 0; c4 < 32; ++c4) {
            float4 wq = wbase[c4*64];
            #pragma unroll
            for (int s8 = 0; s8 < 8; ++s8) {
                if (okv[s8]) {
                    float4 f4 = sF[wv*8 + s8][c4];
                    acc[s8] += f4.x*wq.x + f4.y*wq.y + f4.z*wq.z + f4.w*wq.w;
                }
            }
        }
        #pragma unroll
        for (int s8 = 0; s8 < 8; ++s8) {
            if (okv[s8]) atomicAdd(&accS[cell[s8]*64 + co], acc[s8]);
        }
    }
}

// ---------------------------------------------------------------------------
// Dense conv3d via MFMA 16x16x32 bf16, 3-product hi/lo split (fp32-accurate
// to ~2^-18 relative). Block = (od, oh) x 64ow x 64co; 4 waves split
// 2(ow-half) x 2(co-half); acc = 2mt x 2ct x f32x4.
// Input staged per (kd,kh): one row 66w x 64ci, fp32 -> bn+relu (gact) ->
// hi/lo bf16 in LDS [ci-group g][w] (16B chunks). Weights from global in
// prepacked fragment order. Epilogue: bn+relu; channels-last via LDS
// transpose (conv2) or direct f32x4 stores (conv3 co-major, sW==1).
// ---------------------------------------------------------------------------
__global__ __launch_bounds__(256) void k_convm(
    const float* __restrict__ src, int src_h0, long src_dpitch,
    float* __restrict__ dst, int dst_h0, long sC, long sD, long sH, long sW,
    const bf16_t* __restrict__ wph, const bf16_t* __restrict__ wpl,
    const float* __restrict__ gact,
    const float* __restrict__ gout, const float* __restrict__ bout,
    int D_in, int d_stride, int d_pad, int y0)
{
    int oh = y0 + (int)blockIdx.y;
    if ((unsigned)oh >= (unsigned)GH) return;          // uniform

    __shared__ __align__(16) char smem[17408];
    bf16_t* sAh = (bf16_t*)smem;           // [8 g][66 w][8 bf16] = 8448 B
    bf16_t* sAl = (bf16_t*)(smem + 8448);  // 8448 B
    float*  sOut = (float*)smem;           // [64 w][68] fp32 = 17408 B (overlay)

    int t = threadIdx.x;
    int lane = t & 63, wv = t >> 6;
    int wl = lane & 15, kg = lane >> 4;
    int mh = wv >> 1, cth = wv & 1;
    int w0 = (int)blockIdx.x * 64;
    int od = (int)blockIdx.z;

    f32x4 acc[2][2];
    #pragma unroll
    for (int a = 0; a < 2; ++a)
        #pragma unroll
        for (int b = 0; b < 2; ++b) acc[a][b] = (f32x4){0.f, 0.f, 0.f, 0.f};

    const bf16x8* WH = (const bf16x8*)wph;
    const bf16x8* WL = (const bf16x8*)wpl;

    for (int kd = 0; kd < 3; ++kd) {
        int dp = od*d_stride + kd - d_pad;
        if (dp < 0 || dp >= D_in) continue;            // uniform
        const float* sdb = src + dp*src_dpitch;
        for (int kh = 0; kh < 3; ++kh) {
            int hp = oh + kh - 1;
            bool vh = ((unsigned)hp < (unsigned)GH);
            const float* srow = sdb + (long)(hp - src_h0) * (GW*64);
            __syncthreads();                           // prior phase reads done
            for (int c = t; c < 528; c += 256) {
                int g = c & 7, w = c >> 3;
                int gw = w0 - 1 + w;
                f32x4 v0 = {0.f,0.f,0.f,0.f}, v1 = {0.f,0.f,0.f,0.f};
                if (vh && (unsigned)gw < (unsigned)GW) {
                    const float* p = srow + (long)gw*64 + g*8;
                    v0 = *(const f32x4*)p;
                    v1 = *(const f32x4*)(p + 4);
                    f32x4 ga = *(const f32x4*)(gact + g*8);
                    f32x4 gb = *(const f32x4*)(gact + g*8 + 4);
                    f32x4 ba = *(const f32x4*)(gact + 64 + g*8);
                    f32x4 bb = *(const f32x4*)(gact + 64 + g*8 + 4);
                    #pragma unroll
                    for (int e = 0; e < 4; ++e) {
                        v0[e] = fmaxf(v0[e]*ga[e] + ba[e], 0.f);
                        v1[e] = fmaxf(v1[e]*gb[e] + bb[e], 0.f);
                    }
                }
                bf16x8 hi, lo;
                #pragma unroll
                for (int e = 0; e < 4; ++e) {
                    bf16_t h0 = (bf16_t)v0[e];
                    hi[e] = h0; lo[e] = (bf16_t)(v0[e] - (float)h0);
                    bf16_t h1 = (bf16_t)v1[e];
                    hi[4+e] = h1; lo[4+e] = (bf16_t)(v1[e] - (float)h1);
                }
                *(bf16x8*)&sAh[(g*66 + w)*8] = hi;
                *(bf16x8*)&sAl[(g*66 + w)*8] = lo;
            }
            __syncthreads();
            #pragma unroll
            for (int h = 0; h < 2; ++h) {
                #pragma unroll
                for (int kw = 0; kw < 3; ++kw) {
                    int s = ((kd*3 + kh)*3 + kw)*2 + h;
                    long fb = (long)(s*4 + cth*2)*64 + lane;
                    bf16x8 B0h = WH[fb],      B0l = WL[fb];
                    bf16x8 B1h = WH[fb + 64], B1l = WL[fb + 64];
                    #pragma unroll
                    for (int mt = 0; mt < 2; ++mt) {
                        int ai = ((h*4 + kg)*66 + (mh*2 + mt)*16 + kw + wl)*8;
                        bf16x8 Ah = *(const bf16x8*)&sAh[ai];
                        bf16x8 Al = *(const bf16x8*)&sAl[ai];
                        acc[mt][0] = __builtin_amdgcn_mfma_f32_16x16x32_bf16(Ah, B0h, acc[mt][0], 0, 0, 0);
                        acc[mt][0] = __builtin_amdgcn_mfma_f32_16x16x32_bf16(Ah, B0l, acc[mt][0], 0, 0, 0);
                        acc[mt][0] = __builtin_amdgcn_mfma_f32_16x16x32_bf16(Al, B0h, acc[mt][0], 0, 0, 0);
                        acc[mt][1] = __builtin_amdgcn_mfma_f32_16x16x32_bf16(Ah, B1h, acc[mt][1], 0, 0, 0);
                        acc[mt][1] = __builtin_amdgcn_mfma_f32_16x16x32_bf16(Ah, B1l, acc[mt][1], 0, 0, 0);
                        acc[mt][1] = __builtin_amdgcn_mfma_f32_16x16x32_bf16(Al, B1h, acc[mt][1], 0, 0, 0);
                    }
                }
            }
        }
    }

    // ---- epilogue ----
    float so[2], bo[2];
    #pragma unroll
    for (int ct = 0; ct < 2; ++ct) {
        int co = (cth*2 + ct)*16 + wl;
        so[ct] = gout[co]*BNC; bo[ct] = bout[co];
    }
    if (sW == 1) {
        // co-major (conv3 -> d_out): lane holds 4 consecutive ow -> f32x4 store
        #pragma unroll
        for (int mt = 0; mt < 2; ++mt) {
            int ow = w0 + (mh*2 + mt)*16 + kg*4;
            if (ow < GW) {
                #pragma unroll
                for (int ct = 0; ct < 2; ++ct) {
                    int co = (cth*2 + ct)*16 + wl;
                    f32x4 r;
                    #pragma unroll
                    for (int e = 0; e < 4; ++e)
                        r[e] = fmaxf(acc[mt][ct][e]*so[ct] + bo[ct], 0.f);
                    *(f32x4*)&dst[(long)co*sC + (long)od*sD + (long)(oh - dst_h0)*sH + ow] = r;
                }
            }
        }
    } else {
        // channels-last (conv2 -> actS): LDS transpose then float4 stores
        __syncthreads();      // done reading sA (overlay!)
        #pragma unroll
        for (int mt = 0; mt < 2; ++mt)
            #pragma unroll
            for (int ct = 0; ct < 2; ++ct) {
                int co = (cth*2 + ct)*16 + wl;
                #pragma unroll
                for (int e = 0; e < 4; ++e) {
                    int owl = (mh*2 + mt)*16 + kg*4 + e;
                    sOut[owl*68 + co] = fmaxf(acc[mt][ct][e]*so[ct] + bo[ct], 0.f);
                }
            }
        __syncthreads();
        for (int f = t; f < 1024; f += 256) {
            int w = f >> 4, c4 = f & 15;
            if (w0 + w < GW) {
                float4 v = *(const float4*)&sOut[w*68 + c4*4];
                *(float4*)&dst[(long)od*sD + (long)(oh - dst_h0)*sH + (long)(w0 + w)*64 + c4*4] = v;
            }
        }
    }
}

// ---------------------------------------------------------------------------
extern "C" void kernel_launch(void* const* d_in, const int* in_sizes, int n_in,
                              void* d_out, int out_size, void* d_ws, size_t ws_size,
                              hipStream_t stream)
{
    const float* feats = (const float*)d_in[0];
    const int*   nvox  = (const int*)d_in[1];
    const int*   coors = (const int*)d_in[2];
    const float* w1  = (const float*)d_in[4];
    const float* g1  = (const float*)d_in[5];
    const float* b1  = (const float*)d_in[6];
    const float* w2  = (const float*)d_in[7];
    const float* g2  = (const float*)d_in[8];
    const float* b2  = (const float*)d_in[9];
    const float* wl  = (const float*)d_in[10];
    const float* gl  = (const float*)d_in[11];
    const float* bl  = (const float*)d_in[12];
    const float* wc1 = (const float*)d_in[13];
    const float* gc1 = (const float*)d_in[14];
    const float* bc1 = (const float*)d_in[15];
    const float* wc2 = (const float*)d_in[16];
    const float* gc2 = (const float*)d_in[17];
    const float* bc2 = (const float*)d_in[18];
    const float* wc3 = (const float*)d_in[19];
    const float* gc3 = (const float*)d_in[20];
    const float* bc3 = (const float*)d_in[21];

    int N = in_sizes[1];            // 20000 voxels

    auto al = [](size_t b) { return (b + 255) & ~(size_t)255; };

    size_t winB = al((size_t)10*GH*GW*4);
    size_t voxB = al((size_t)N*128*4);
    size_t w1B  = al((size_t)27*128*64*4);
    size_t wlB  = al((size_t)128*128*4);
    size_t wpB  = al((size_t)13824*8*2);   // one packed bf16 weight buffer
    int NS = 16;
    const int cand[5] = {1, 2, 4, 8, 16};
    for (int k = 0; k < 5; ++k) {
        int ns = cand[k], sh = 400/ns, ar = sh + 4, xr = sh + 2;
        size_t tot = al((size_t)5*ar*GW*64*4) + al((size_t)3*xr*GW*64*4)
                   + winB + voxB + w1B + wlB + 4*wpB + al((size_t)ns*N*4) + 4096;
        if (tot + (1<<16) <= ws_size) { NS = ns; break; }
    }
    int SH = 400/NS, AR = SH + 4, XR = SH + 2;

    char* ws = (char*)d_ws;
    size_t off = 0;
    auto alloc = [&](size_t bytes) -> void* {
        void* p = ws + off; off += al(bytes); return p;
    };
    size_t accB = (size_t)5*AR*GW*64*4;
    size_t actB = (size_t)3*XR*GW*64*4;
    float*  accS   = (float*)alloc(accB);
    float*  actS   = (float*)alloc(actB);
    int*    winner = (int*)alloc((size_t)10*GH*GW*4);
    float*  voxw   = (float*)alloc((size_t)N*128*4);
    float*  wt1    = (float*)alloc((size_t)27*128*64*4);
    float*  wtl    = (float*)alloc((size_t)128*128*4);
    bf16_t* wp2h   = (bf16_t*)alloc(wpB);
    bf16_t* wp2l   = (bf16_t*)alloc(wpB);
    bf16_t* wp3h   = (bf16_t*)alloc(wpB);
    bf16_t* wp3l   = (bf16_t*)alloc(wpB);
    float*  gact   = (float*)alloc(256*4);
    int*    list   = (int*)alloc((size_t)NS*N*4);
    int*    cnt    = (int*)alloc(256);

    hipMemsetAsync(winner, 0xFF, (size_t)10*GH*GW*4, stream);
    hipMemsetAsync(cnt, 0, 256, stream);

    k_tr_w<<<(27*128*64 + 255)/256, 256, 0, stream>>>(wc1, wt1, 128, 64);
    k_tr_lin<<<64, 256, 0, stream>>>(wl, wtl);
    k_packw<<<54, 256, 0, stream>>>(wc2, wp2h, wp2l);
    k_packw<<<54, 256, 0, stream>>>(wc3, wp3h, wp3l);
    k_prep<<<1, 256, 0, stream>>>(gc1, bc1, gact);

    k_winner<<<(N + 255)/256, 256, 0, stream>>>(coors, winner, N);
    k_lists<<<(N + 255)/256, 256, 0, stream>>>(coors, list, cnt, N, SH, NS);
    k_vfe<<<N, 128, 0, stream>>>(feats, nvox, w1, g1, b1, w2, g2, b2, wtl, gl, bl, voxw);

    for (int s = 0; s < NS; ++s) {
        hipMemsetAsync(accS, 0, accB, stream);
        k_scat<<<(N + 31)/32, 256, 0, stream>>>(
            (const float4*)voxw, coors, winner, (const float4*)wt1,
            accS, list + (long)s*N, cnt + s, s*SH - 2, AR);
        // conv2 (MFMA): src accS raw (fuse bn1+relu via gact), dst actS
        // channels-last (sW=64), bn2+relu on write
        k_convm<<<dim3(6, SH + 2, 3), 256, 0, stream>>>(
            accS, s*SH - 2, (long)AR*GW*64,
            actS, s*SH - 1, 1L, (long)XR*GW*64, (long)GW*64, 64L,
            wp2h, wp2l, gact, gc2, bc2,
            5, 1, 0, s*SH - 1);
        // conv3 (MFMA): src actS activated (identity gact+128); dst d_out
        // co-major (sW=1), channel = co*2 + od
        k_convm<<<dim3(6, SH, 2), 256, 0, stream>>>(
            actS, s*SH - 1, (long)XR*GW*64,
            (float*)d_out, 0, (long)2*GH*GW, (long)GH*GW, (long)GW, 1L,
            wp3h, wp3l, gact + 128, gc3, bc3,
            3, 2, 1, s*SH);
    }
}

// Round 7
// 1471.147 us; speedup vs baseline: 18.7477x; 1.1110x over previous
//
#include <hip/hip_runtime.h>
#include <hip/hip_bf16.h>

#define BNC 0.99950037f   // 1/sqrt(1+1e-3), BN eval scale factor
#define GH 400
#define GW 352

typedef __bf16 bf16_t;
typedef __bf16 bf16x8 __attribute__((ext_vector_type(8)));
typedef float f32x4 __attribute__((ext_vector_type(4)));

// ---------------------------------------------------------------------------
// Winner grid: last voxel index wins for duplicate cells (matches np fancy-set)
// ---------------------------------------------------------------------------
__global__ void k_winner(const int* __restrict__ coors, int* __restrict__ winner, int N) {
    int i = blockIdx.x * 256 + threadIdx.x;
    if (i >= N) return;
    int d = coors[i*4+1], h = coors[i*4+2], w = coors[i*4+3];
    atomicMax(&winner[(d*GH + h)*GW + w], i);
}

// ---------------------------------------------------------------------------
__global__ void k_lists(const int* __restrict__ coors, int* __restrict__ list,
                        int* __restrict__ cnt, int N, int SH, int NS) {
    int i = blockIdx.x * 256 + threadIdx.x;
    if (i >= N) return;
    int h = coors[i*4+2];
    for (int s = 0; s < NS; ++s) {
        int lo = s*SH - 3, hi = s*SH + SH + 3;
        if (h >= lo && h < hi) {
            int p = atomicAdd(&cnt[s], 1);
            list[(long)s*N + p] = i;
        }
    }
}

// ---------------------------------------------------------------------------
// Weight transpose for conv1/scatter: OIDHW -> [tap][ci4][co][4]
// ---------------------------------------------------------------------------
__global__ void k_tr_w(const float* __restrict__ w, float* __restrict__ wt, int CI, int CO) {
    int idx = blockIdx.x * 256 + threadIdx.x;
    int total = 27 * CI * CO;
    if (idx >= total) return;
    int j   = idx & 3;
    int t1  = idx >> 2;
    int co  = t1 % CO;
    int t2  = t1 / CO;
    int ci4 = t2 % (CI/4);
    int tap = t2 / (CI/4);
    int ci  = ci4*4 + j;
    wt[idx] = w[(co*CI + ci)*27 + tap];
}

// Linear-layer weight transpose: wl[u][c] -> WT[c][u]
__global__ void k_tr_lin(const float* __restrict__ wl, float* __restrict__ WT) {
    int idx = blockIdx.x * 256 + threadIdx.x;
    if (idx >= 16384) return;
    int u = idx & 127, c = idx >> 7;
    WT[c*128 + u] = wl[u*128 + c];
}

// Input-activation table for convs: [0:64) gc1*BNC, [64:128) bc1,
// [128:192) 1.0, [192:256) 0.0 (identity block for conv3)
__global__ void k_prep(const float* __restrict__ g, const float* __restrict__ b,
                       float* __restrict__ out) {
    int i = threadIdx.x;
    if (i < 64)       out[i] = g[i] * BNC;
    else if (i < 128) out[i] = b[i-64];
    else if (i < 192) out[i] = 1.f;
    else              out[i] = 0.f;
}

// ---------------------------------------------------------------------------
// Pack 64x64x27 conv weights (OIDHW fp32) into MFMA B-fragment order, split
// into hi/lo bf16. Frag index fb = (s*4 + ct)*64 + lane, s = tap*2 + h.
// Lane l of B[k][n]: n(co) = ct*16 + (l&15), k(ci) = h*32 + (l>>4)*8 + j.
// ---------------------------------------------------------------------------
__global__ void k_packw(const float* __restrict__ w, bf16_t* __restrict__ wh,
                        bf16_t* __restrict__ wlo) {
    int i = blockIdx.x * 256 + threadIdx.x;    // over 54*4*64 = 13824 frag-lanes
    if (i >= 13824) return;
    int lane = i & 63, ct = (i >> 6) & 3, s = i >> 8;
    int tap = s >> 1, h = s & 1;
    int kg = lane >> 4, wl = lane & 15;
    int co = ct*16 + wl;
    #pragma unroll
    for (int j = 0; j < 8; ++j) {
        int ci = h*32 + kg*8 + j;
        float v = w[(co*64 + ci)*27 + tap];
        bf16_t hi = (bf16_t)v;
        wh[(long)i*8 + j]  = hi;
        wlo[(long)i*8 + j] = (bf16_t)(v - (float)hi);
    }
}

// ---------------------------------------------------------------------------
// VFE: one block (128 thr) per voxel. Agg-split form: for both layer2 and
// linear, input = [h(t) | agg] where agg is row-invariant, so
// out[t] = h[t] @ W_top + (agg @ W_bot), the second term computed ONCE per
// voxel. Halves K for layer2/linear and removes agg-column storage
// (LDS 30.2 -> ~19.3 KB). Reference quirks preserved: mean over ALL 35 rows
// / num_voxels; layer1 agg over ALL rows; layer2 agg includes relu(b2) for
// zero rows when nv<35.
// ---------------------------------------------------------------------------
__global__ __launch_bounds__(128) void k_vfe(
    const float* __restrict__ feats, const int* __restrict__ nvox,
    const float* __restrict__ w1, const float* __restrict__ g1g, const float* __restrict__ b1g,
    const float* __restrict__ w2g, const float* __restrict__ g2g, const float* __restrict__ b2g,
    const float* __restrict__ WT, const float* __restrict__ glg, const float* __restrict__ blg,
    float* __restrict__ voxelwise)
{
    __shared__ float F[35*8];        // cols 0..3 feat, 4..6 rel, 7 zero
    __shared__ float W1s[16*8];
    __shared__ float SG1[16], SB1[16];
    __shared__ float X1[35*20];      // h-part only, stride 20 (5 float4)
    __shared__ float X2[35*68];      // h-part only, stride 68 (17 float4)
    __shared__ float RED[8*128];
    __shared__ float AGG1[16];
    __shared__ float AGG2[64];
    __shared__ float Y2B[64];        // agg1 @ W2[:,16:32]
    __shared__ float YB[128];        // agg2 @ WL[:,64:128]
    __shared__ float MEANS[3];

    int tid = threadIdx.x;
    int vox = blockIdx.x;
    int nv  = nvox[vox];

    const float* fsrc = feats + (long)vox * 140;
    for (int idx = tid; idx < 140; idx += 128) { int t = idx>>2, c = idx&3; F[t*8+c] = fsrc[idx]; }
    if (tid < 35) F[tid*8+7] = 0.f;
    if (tid < 112) { int u = tid/7, c = tid - u*7; W1s[u*8+c] = w1[tid]; }
    if (tid < 16)  { W1s[tid*8+7] = 0.f; SG1[tid] = g1g[tid]*BNC; SB1[tid] = b1g[tid]; }
    __syncthreads();

    if (tid < 3) {
        float s = 0.f;
        for (int t = 0; t < 35; ++t) s += F[t*8 + tid];
        MEANS[tid] = s / (float)nv;
    }
    __syncthreads();
    for (int idx = tid; idx < 105; idx += 128) { int t = idx/3, c = idx - t*3; F[t*8+4+c] = F[t*8+c] - MEANS[c]; }
    __syncthreads();

    // ---- layer1: all 35 rows (agg1 must see unmasked rows) ----
    {
        const float4* Ff4  = (const float4*)F;
        const float4* W1f4 = (const float4*)W1s;
        for (int idx = tid; idx < 560; idx += 128) {
            int t = idx >> 4, u = idx & 15;
            float4 a0 = Ff4[t*2], a1 = Ff4[t*2+1];
            float4 b0 = W1f4[u*2], b1v = W1f4[u*2+1];
            float a = a0.x*b0.x + a0.y*b0.y + a0.z*b0.z + a0.w*b0.w
                    + a1.x*b1v.x + a1.y*b1v.y + a1.z*b1v.z + a1.w*b1v.w;
            X1[t*20+u] = fmaxf(a*SG1[u] + SB1[u], 0.f);
        }
    }
    __syncthreads();
    if (tid < 16) {
        float m = 0.f;
        for (int t = 0; t < 35; ++t) m = fmaxf(m, X1[t*20+tid]);
        AGG1[tid] = m;
    }
    __syncthreads();
    // y2b[u] = agg1 . w2[u][16:32]
    if (tid < 64) {
        const float4* wsrc = (const float4*)(w2g + tid*32 + 16);
        const float4* A1f4 = (const float4*)AGG1;
        float a = 0.f;
        #pragma unroll
        for (int q = 0; q < 4; ++q) {
            float4 w4 = wsrc[q], x4 = A1f4[q];
            a += x4.x*w4.x + x4.y*w4.y + x4.z*w4.z + x4.w*w4.w;
        }
        Y2B[tid] = a;
    }
    __syncthreads();

    // ---- layer2 (K=16): all 128 threads, weights in registers ----
    {
        int u = tid & 63, tg = tid >> 6;
        float w2r[16];
        const float4* wsrc = (const float4*)(w2g + u*32);
        #pragma unroll
        for (int q = 0; q < 4; ++q) {
            float4 w4 = wsrc[q];
            w2r[q*4] = w4.x; w2r[q*4+1] = w4.y; w2r[q*4+2] = w4.z; w2r[q*4+3] = w4.w;
        }
        float su = g2g[u]*BNC, bu = b2g[u];
        float yb2 = Y2B[u];
        float lm = (nv < 35) ? fmaxf(bu, 0.f) : 0.f;   // zero-row contribution
        for (int t = tg; t < nv; t += 2) {
            const float4* xr = (const float4*)(X1 + t*20);
            float a = yb2;
            #pragma unroll
            for (int q = 0; q < 4; ++q) {
                float4 x4 = xr[q];
                a += x4.x*w2r[q*4] + x4.y*w2r[q*4+1] + x4.z*w2r[q*4+2] + x4.w*w2r[q*4+3];
            }
            float h = fmaxf(a*su + bu, 0.f);
            X2[t*68 + u] = h;
            lm = fmaxf(lm, h);
        }
        RED[tg*64 + u] = lm;
    }
    __syncthreads();
    if (tid < 64) AGG2[tid] = fmaxf(RED[tid], RED[64+tid]);
    __syncthreads();
    // yb[u] = agg2 . WL[u][64:128]  (WT rows 64..127, coalesced over u)
    {
        float a = 0.f;
        for (int c = 0; c < 64; ++c) a = fmaf(AGG2[c], WT[(64 + c)*128 + tid], a);
        YB[tid] = a;
    }
    __syncthreads();

    // ---- linear (K=64) over rows t<nv: thread = (tg4 0..7) x (ug 0..15) ----
    {
        int ug = tid & 15, tg4 = tid >> 4;
        int u0 = ug * 8;
        int kmax = (nv > tg4) ? ((nv - tg4 + 7) >> 3) : 0;
        float acc[5][8];
        #pragma unroll
        for (int k = 0; k < 5; ++k)
            #pragma unroll
            for (int j = 0; j < 8; ++j) acc[k][j] = 0.f;

        const float4* X2f4 = (const float4*)X2;
        const float4* WTf4 = (const float4*)WT;
        for (int c4 = 0; c4 < 16; ++c4) {
            float4 wv[8];
            #pragma unroll
            for (int cc = 0; cc < 4; ++cc) {
                wv[cc*2]   = WTf4[(c4*4+cc)*32 + ug*2];
                wv[cc*2+1] = WTf4[(c4*4+cc)*32 + ug*2 + 1];
            }
            #pragma unroll
            for (int k = 0; k < 5; ++k) {
                if (k < kmax) {
                    int t = tg4 + (k << 3);
                    float4 x4 = X2f4[t*17 + c4];
                    #pragma unroll
                    for (int cc = 0; cc < 4; ++cc) {
                        float xs = (cc == 0) ? x4.x : (cc == 1) ? x4.y : (cc == 2) ? x4.z : x4.w;
                        acc[k][0] = fmaf(xs, wv[cc*2].x,   acc[k][0]);
                        acc[k][1] = fmaf(xs, wv[cc*2].y,   acc[k][1]);
                        acc[k][2] = fmaf(xs, wv[cc*2].z,   acc[k][2]);
                        acc[k][3] = fmaf(xs, wv[cc*2].w,   acc[k][3]);
                        acc[k][4] = fmaf(xs, wv[cc*2+1].x, acc[k][4]);
                        acc[k][5] = fmaf(xs, wv[cc*2+1].y, acc[k][5]);
                        acc[k][6] = fmaf(xs, wv[cc*2+1].z, acc[k][6]);
                        acc[k][7] = fmaf(xs, wv[cc*2+1].w, acc[k][7]);
                    }
                }
            }
        }
        float4 g0 = *(const float4*)(glg + u0), g1v = *(const float4*)(glg + u0 + 4);
        float4 b0 = *(const float4*)(blg + u0), b1v = *(const float4*)(blg + u0 + 4);
        float4 y0 = *(const float4*)(YB + u0),  y1v = *(const float4*)(YB + u0 + 4);
        float sg[8] = {g0.x*BNC, g0.y*BNC, g0.z*BNC, g0.w*BNC,
                       g1v.x*BNC, g1v.y*BNC, g1v.z*BNC, g1v.w*BNC};
        float sb[8] = {b0.x, b0.y, b0.z, b0.w, b1v.x, b1v.y, b1v.z, b1v.w};
        float yv[8] = {y0.x, y0.y, y0.z, y0.w, y1v.x, y1v.y, y1v.z, y1v.w};
        float m[8];
        #pragma unroll
        for (int j = 0; j < 8; ++j) m[j] = 0.f;
        #pragma unroll
        for (int k = 0; k < 5; ++k) {
            if (k < kmax) {
                #pragma unroll
                for (int j = 0; j < 8; ++j)
                    m[j] = fmaxf(m[j], fmaxf((acc[k][j] + yv[j])*sg[j] + sb[j], 0.f));
            }
        }
        #pragma unroll
        for (int j = 0; j < 8; ++j) RED[tg4*128 + u0 + j] = m[j];
    }
    __syncthreads();
    {
        float m = RED[tid];
        #pragma unroll
        for (int r = 1; r < 8; ++r) m = fmaxf(m, RED[r*128 + tid]);
        voxelwise[(long)vox*128 + tid] = m;
    }
}

// ---------------------------------------------------------------------------
// conv1 as sparse scatter (unchanged).
// ---------------------------------------------------------------------------
__global__ __launch_bounds__(256) void k_scat(
    const float4* __restrict__ voxf4, const int* __restrict__ coors,
    const int* __restrict__ winner, const float4* __restrict__ Wt1,
    float* __restrict__ accS, const int* __restrict__ list,
    const int* __restrict__ cnt, int h_lo, int AR)
{
    __shared__ float4 sF[32][32];
    __shared__ int sI[32], sD[32], sH_[32], sWc[32], sV[32];
    int tid = threadIdx.x;
    int cn = cnt[0];
    int v0 = blockIdx.x * 32;
    if (v0 >= cn) return;

    if (tid < 32) {
        int slot = v0 + tid;
        int i = -1, d = 0, h = 0, w = 0, ok = 0;
        if (slot < cn) {
            i = list[slot];
            d = coors[i*4+1]; h = coors[i*4+2]; w = coors[i*4+3];
            ok = (winner[(d*GH + h)*GW + w] == i);
        }
        sI[tid] = i; sD[tid] = d; sH_[tid] = h; sWc[tid] = w; sV[tid] = ok;
    }
    __syncthreads();
    for (int idx = tid; idx < 1024; idx += 256) {
        int v = idx >> 5, c = idx & 31;
        int vi = sI[v];
        if (vi >= 0) sF[v][c] = voxf4[(long)vi*32 + c];
    }
    __syncthreads();

    int co = tid & 63, wv = tid >> 6;
    for (int tap = 0; tap < 27; ++tap) {
        int kd = tap/9, kh = (tap/3)%3, kw = tap%3;
        bool okv[8]; long cell[8];
        bool anyv = false;
        #pragma unroll
        for (int s8 = 0; s8 < 8; ++s8) {
            int v = wv*8 + s8;
            int od2 = sD[v] + 1 - kd;
            int oh  = sH_[v] + 1 - kh;
            int ow  = sWc[v] + 1 - kw;
            okv[s8] = sV[v] && !(od2 & 1) && (unsigned)od2 < 10u
                      && oh >= 0 && oh < GH && oh >= h_lo && oh < h_lo + AR
                      && (unsigned)ow < (unsigned)GW;
            anyv |= okv[s8];
            cell[s8] = okv[s8] ? ((long)((od2>>1)*AR + (oh - h_lo))*GW + ow) : 0;
        }
        if (!anyv) continue;   // wave-uniform
        float acc[8];
        #pragma unroll
        for (int s8 = 0; s8 < 8; ++s8) acc[s8] = 0.f;
        const float4* wbase = Wt1 + (long)tap*2048 + co;
        for (int c4 = 0; c4 < 32; ++c4) {
            float4 wq = wbase[c4*64];
            #pragma unroll
            for (int s8 = 0; s8 < 8; ++s8) {
                if (okv[s8]) {
                    float4 f4 = sF[wv*8 + s8][c4];
                    acc[s8] += f4.x*wq.x + f4.y*wq.y + f4.z*wq.z + f4.w*wq.w;
                }
            }
        }
        #pragma unroll
        for (int s8 = 0; s8 < 8; ++s8) {
            if (okv[s8]) atomicAdd(&accS[cell[s8]*64 + co], acc[s8]);
        }
    }
}

// ---------------------------------------------------------------------------
// Dense conv3d via MFMA 16x16x32 bf16, 3-product hi/lo split (unchanged).
// ---------------------------------------------------------------------------
__global__ __launch_bounds__(256) void k_convm(
    const float* __restrict__ src, int src_h0, long src_dpitch,
    float* __restrict__ dst, int dst_h0, long sC, long sD, long sH, long sW,
    const bf16_t* __restrict__ wph, const bf16_t* __restrict__ wpl,
    const float* __restrict__ gact,
    const float* __restrict__ gout, const float* __restrict__ bout,
    int D_in, int d_stride, int d_pad, int y0)
{
    int oh = y0 + (int)blockIdx.y;
    if ((unsigned)oh >= (unsigned)GH) return;          // uniform

    __shared__ __align__(16) char smem[17408];
    bf16_t* sAh = (bf16_t*)smem;           // [8 g][66 w][8 bf16] = 8448 B
    bf16_t* sAl = (bf16_t*)(smem + 8448);  // 8448 B
    float*  sOut = (float*)smem;           // [64 w][68] fp32 = 17408 B (overlay)

    int t = threadIdx.x;
    int lane = t & 63, wv = t >> 6;
    int wl = lane & 15, kg = lane >> 4;
    int mh = wv >> 1, cth = wv & 1;
    int w0 = (int)blockIdx.x * 64;
    int od = (int)blockIdx.z;

    f32x4 acc[2][2];
    #pragma unroll
    for (int a = 0; a < 2; ++a)
        #pragma unroll
        for (int b = 0; b < 2; ++b) acc[a][b] = (f32x4){0.f, 0.f, 0.f, 0.f};

    const bf16x8* WH = (const bf16x8*)wph;
    const bf16x8* WL = (const bf16x8*)wpl;

    for (int kd = 0; kd < 3; ++kd) {
        int dp = od*d_stride + kd - d_pad;
        if (dp < 0 || dp >= D_in) continue;            // uniform
        const float* sdb = src + dp*src_dpitch;
        for (int kh = 0; kh < 3; ++kh) {
            int hp = oh + kh - 1;
            bool vh = ((unsigned)hp < (unsigned)GH);
            const float* srow = sdb + (long)(hp - src_h0) * (GW*64);
            __syncthreads();                           // prior phase reads done
            for (int c = t; c < 528; c += 256) {
                int g = c & 7, w = c >> 3;
                int gw = w0 - 1 + w;
                f32x4 v0 = {0.f,0.f,0.f,0.f}, v1 = {0.f,0.f,0.f,0.f};
                if (vh && (unsigned)gw < (unsigned)GW) {
                    const float* p = srow + (long)gw*64 + g*8;
                    v0 = *(const f32x4*)p;
                    v1 = *(const f32x4*)(p + 4);
                    f32x4 ga = *(const f32x4*)(gact + g*8);
                    f32x4 gb = *(const f32x4*)(gact + g*8 + 4);
                    f32x4 ba = *(const f32x4*)(gact + 64 + g*8);
                    f32x4 bb = *(const f32x4*)(gact + 64 + g*8 + 4);
                    #pragma unroll
                    for (int e = 0; e < 4; ++e) {
                        v0[e] = fmaxf(v0[e]*ga[e] + ba[e], 0.f);
                        v1[e] = fmaxf(v1[e]*gb[e] + bb[e], 0.f);
                    }
                }
                bf16x8 hi, lo;
                #pragma unroll
                for (int e = 0; e < 4; ++e) {
                    bf16_t h0 = (bf16_t)v0[e];
                    hi[e] = h0; lo[e] = (bf16_t)(v0[e] - (float)h0);
                    bf16_t h1 = (bf16_t)v1[e];
                    hi[4+e] = h1; lo[4+e] = (bf16_t)(v1[e] - (float)h1);
                }
                *(bf16x8*)&sAh[(g*66 + w)*8] = hi;
                *(bf16x8*)&sAl[(g*66 + w)*8] = lo;
            }
            __syncthreads();
            #pragma unroll
            for (int h = 0; h < 2; ++h) {
                #pragma unroll
                for (int kw = 0; kw < 3; ++kw) {
                    int s = ((kd*3 + kh)*3 + kw)*2 + h;
                    long fb = (long)(s*4 + cth*2)*64 + lane;
                    bf16x8 B0h = WH[fb],      B0l = WL[fb];
                    bf16x8 B1h = WH[fb + 64], B1l = WL[fb + 64];
                    #pragma unroll
                    for (int mt = 0; mt < 2; ++mt) {
                        int ai = ((h*4 + kg)*66 + (mh*2 + mt)*16 + kw + wl)*8;
                        bf16x8 Ah = *(const bf16x8*)&sAh[ai];
                        bf16x8 Al = *(const bf16x8*)&sAl[ai];
                        acc[mt][0] = __builtin_amdgcn_mfma_f32_16x16x32_bf16(Ah, B0h, acc[mt][0], 0, 0, 0);
                        acc[mt][0] = __builtin_amdgcn_mfma_f32_16x16x32_bf16(Ah, B0l, acc[mt][0], 0, 0, 0);
                        acc[mt][0] = __builtin_amdgcn_mfma_f32_16x16x32_bf16(Al, B0h, acc[mt][0], 0, 0, 0);
                        acc[mt][1] = __builtin_amdgcn_mfma_f32_16x16x32_bf16(Ah, B1h, acc[mt][1], 0, 0, 0);
                        acc[mt][1] = __builtin_amdgcn_mfma_f32_16x16x32_bf16(Ah, B1l, acc[mt][1], 0, 0, 0);
                        acc[mt][1] = __builtin_amdgcn_mfma_f32_16x16x32_bf16(Al, B1h, acc[mt][1], 0, 0, 0);
                    }
                }
            }
        }
    }

    // ---- epilogue ----
    float so[2], bo[2];
    #pragma unroll
    for (int ct = 0; ct < 2; ++ct) {
        int co = (cth*2 + ct)*16 + wl;
        so[ct] = gout[co]*BNC; bo[ct] = bout[co];
    }
    if (sW == 1) {
        #pragma unroll
        for (int mt = 0; mt < 2; ++mt) {
            int ow = w0 + (mh*2 + mt)*16 + kg*4;
            if (ow < GW) {
                #pragma unroll
                for (int ct = 0; ct < 2; ++ct) {
                    int co = (cth*2 + ct)*16 + wl;
                    f32x4 r;
                    #pragma unroll
                    for (int e = 0; e < 4; ++e)
                        r[e] = fmaxf(acc[mt][ct][e]*so[ct] + bo[ct], 0.f);
                    *(f32x4*)&dst[(long)co*sC + (long)od*sD + (long)(oh - dst_h0)*sH + ow] = r;
                }
            }
        }
    } else {
        __syncthreads();      // done reading sA (overlay!)
        #pragma unroll
        for (int mt = 0; mt < 2; ++mt)
            #pragma unroll
            for (int ct = 0; ct < 2; ++ct) {
                int co = (cth*2 + ct)*16 + wl;
                #pragma unroll
                for (int e = 0; e < 4; ++e) {
                    int owl = (mh*2 + mt)*16 + kg*4 + e;
                    sOut[owl*68 + co] = fmaxf(acc[mt][ct][e]*so[ct] + bo[ct], 0.f);
                }
            }
        __syncthreads();
        for (int f = t; f < 1024; f += 256) {
            int w = f >> 4, c4 = f & 15;
            if (w0 + w < GW) {
                float4 v = *(const float4*)&sOut[w*68 + c4*4];
                *(float4*)&dst[(long)od*sD + (long)(oh - dst_h0)*sH + (long)(w0 + w)*64 + c4*4] = v;
            }
        }
    }
}

// ---------------------------------------------------------------------------
extern "C" void kernel_launch(void* const* d_in, const int* in_sizes, int n_in,
                              void* d_out, int out_size, void* d_ws, size_t ws_size,
                              hipStream_t stream)
{
    const float* feats = (const float*)d_in[0];
    const int*   nvox  = (const int*)d_in[1];
    const int*   coors = (const int*)d_in[2];
    const float* w1  = (const float*)d_in[4];
    const float* g1  = (const float*)d_in[5];
    const float* b1  = (const float*)d_in[6];
    const float* w2  = (const float*)d_in[7];
    const float* g2  = (const float*)d_in[8];
    const float* b2  = (const float*)d_in[9];
    const float* wl  = (const float*)d_in[10];
    const float* gl  = (const float*)d_in[11];
    const float* bl  = (const float*)d_in[12];
    const float* wc1 = (const float*)d_in[13];
    const float* gc1 = (const float*)d_in[14];
    const float* bc1 = (const float*)d_in[15];
    const float* wc2 = (const float*)d_in[16];
    const float* gc2 = (const float*)d_in[17];
    const float* bc2 = (const float*)d_in[18];
    const float* wc3 = (const float*)d_in[19];
    const float* gc3 = (const float*)d_in[20];
    const float* bc3 = (const float*)d_in[21];

    int N = in_sizes[1];            // 20000 voxels

    auto al = [](size_t b) { return (b + 255) & ~(size_t)255; };

    size_t winB = al((size_t)10*GH*GW*4);
    size_t voxB = al((size_t)N*128*4);
    size_t w1B  = al((size_t)27*128*64*4);
    size_t wlB  = al((size_t)128*128*4);
    size_t wpB  = al((size_t)13824*8*2);   // one packed bf16 weight buffer
    int NS = 16;
    const int cand[5] = {1, 2, 4, 8, 16};
    for (int k = 0; k < 5; ++k) {
        int ns = cand[k], sh = 400/ns, ar = sh + 4, xr = sh + 2;
        size_t tot = al((size_t)5*ar*GW*64*4) + al((size_t)3*xr*GW*64*4)
                   + winB + voxB + w1B + wlB + 4*wpB + al((size_t)ns*N*4) + 4096;
        if (tot + (1<<16) <= ws_size) { NS = ns; break; }
    }
    int SH = 400/NS, AR = SH + 4, XR = SH + 2;

    char* ws = (char*)d_ws;
    size_t off = 0;
    auto alloc = [&](size_t bytes) -> void* {
        void* p = ws + off; off += al(bytes); return p;
    };
    size_t accB = (size_t)5*AR*GW*64*4;
    size_t actB = (size_t)3*XR*GW*64*4;
    float*  accS   = (float*)alloc(accB);
    float*  actS   = (float*)alloc(actB);
    int*    winner = (int*)alloc((size_t)10*GH*GW*4);
    float*  voxw   = (float*)alloc((size_t)N*128*4);
    float*  wt1    = (float*)alloc((size_t)27*128*64*4);
    float*  wtl    = (float*)alloc((size_t)128*128*4);
    bf16_t* wp2h   = (bf16_t*)alloc(wpB);
    bf16_t* wp2l   = (bf16_t*)alloc(wpB);
    bf16_t* wp3h   = (bf16_t*)alloc(wpB);
    bf16_t* wp3l   = (bf16_t*)alloc(wpB);
    float*  gact   = (float*)alloc(256*4);
    int*    list   = (int*)alloc((size_t)NS*N*4);
    int*    cnt    = (int*)alloc(256);

    hipMemsetAsync(winner, 0xFF, (size_t)10*GH*GW*4, stream);
    hipMemsetAsync(cnt, 0, 256, stream);

    k_tr_w<<<(27*128*64 + 255)/256, 256, 0, stream>>>(wc1, wt1, 128, 64);
    k_tr_lin<<<64, 256, 0, stream>>>(wl, wtl);
    k_packw<<<54, 256, 0, stream>>>(wc2, wp2h, wp2l);
    k_packw<<<54, 256, 0, stream>>>(wc3, wp3h, wp3l);
    k_prep<<<1, 256, 0, stream>>>(gc1, bc1, gact);

    k_winner<<<(N + 255)/256, 256, 0, stream>>>(coors, winner, N);
    k_lists<<<(N + 255)/256, 256, 0, stream>>>(coors, list, cnt, N, SH, NS);
    k_vfe<<<N, 128, 0, stream>>>(feats, nvox, w1, g1, b1, w2, g2, b2, wtl, gl, bl, voxw);

    for (int s = 0; s < NS; ++s) {
        hipMemsetAsync(accS, 0, accB, stream);
        k_scat<<<(N + 31)/32, 256, 0, stream>>>(
            (const float4*)voxw, coors, winner, (const float4*)wt1,
            accS, list + (long)s*N, cnt + s, s*SH - 2, AR);
        // conv2 (MFMA): src accS raw (fuse bn1+relu via gact), dst actS
        k_convm<<<dim3(6, SH + 2, 3), 256, 0, stream>>>(
            accS, s*SH - 2, (long)AR*GW*64,
            actS, s*SH - 1, 1L, (long)XR*GW*64, (long)GW*64, 64L,
            wp2h, wp2l, gact, gc2, bc2,
            5, 1, 0, s*SH - 1);
        // conv3 (MFMA): src actS activated (identity gact+128); dst d_out
        k_convm<<<dim3(6, SH, 2), 256, 0, stream>>>(
            actS, s*SH - 1, (long)XR*GW*64,
            (float*)d_out, 0, (long)2*GH*GW, (long)GH*GW, (long)GW, 1L,
            wp3h, wp3l, gact + 128, gc3, bc3,
            3, 2, 1, s*SH);
    }
}